// Round 4
// baseline (1222.921 us; speedup 1.0000x reference)
//
#include <hip/hip_runtime.h>
#include <hip/hip_bf16.h>

typedef unsigned short u16;
typedef unsigned int u32;

static const int DD = 768;
static const int SS = 2048;
static const int BB = 8;
static const int HH = 12;
static const int NBLK = 16;   // S / 128
static const int ROWS = BB * SS;          // 16384
static const size_t AD = (size_t)ROWS * DD;   // activation element count
static const size_t D2 = (size_t)DD * DD;
static const size_t DI = (size_t)DD * 3072;

typedef __attribute__((ext_vector_type(8))) short short8;
typedef __attribute__((ext_vector_type(4))) float f32x4;

union U16x8 { uint4 u; short8 s; };

__device__ __forceinline__ float bl(u32 u) { return __uint_as_float(u << 16); }
__device__ __forceinline__ float bh(u32 u) { return __uint_as_float(u & 0xffff0000u); }
__device__ __forceinline__ u16 f2b(float f) {
    u32 u = __float_as_uint(f);
    u += 0x7fffu + ((u >> 16) & 1u);
    return (u16)(u >> 16);
}
__device__ __forceinline__ u32 pack2(float lo, float hi) {
    return (u32)f2b(lo) | ((u32)f2b(hi) << 16);
}

// async global->LDS, 16B per lane (dest is wave-uniform base + lane*16)
__device__ __forceinline__ void gload16(const u16* g, u16* l) {
    __builtin_amdgcn_global_load_lds(
        (const __attribute__((address_space(1))) void*)g,
        (__attribute__((address_space(3))) void*)l, 16, 0, 0);
}

// ---------------- elementwise f32 -> bf16 cast ----------------
__global__ __launch_bounds__(256) void cast_bf16(const float* __restrict__ x,
                                                 u16* __restrict__ xb, int n) {
    int i = (blockIdx.x * 256 + threadIdx.x) * 4;
    if (i < n) {
        float4 v = *reinterpret_cast<const float4*>(x + i);
        uint2 p;
        p.x = pack2(v.x, v.y);
        p.y = pack2(v.z, v.w);
        *reinterpret_cast<uint2*>(xb + i) = p;
    }
}

// ---------------- cast + transpose: W[K,N] f32 -> WT[N,K] bf16 ----------------
__global__ __launch_bounds__(256) void cast_transpose(const float* __restrict__ W,
                                                      u16* __restrict__ WT,
                                                      int K, int N) {
    __shared__ float tile[32][33];
    int bx = blockIdx.x;  // along N
    int by = blockIdx.y;  // along K
    int tx = threadIdx.x; // 0..31
    int ty = threadIdx.y; // 0..7
#pragma unroll
    for (int i = 0; i < 4; i++) {
        int kr = by * 32 + ty + i * 8;
        tile[ty + i * 8][tx] = W[(size_t)kr * N + bx * 32 + tx];
    }
    __syncthreads();
#pragma unroll
    for (int i = 0; i < 4; i++) {
        int nr = bx * 32 + ty + i * 8;
        WT[(size_t)nr * K + by * 32 + tx] = f2b(tile[tx][ty + i * 8]);
    }
}

// ---------------- 256x256 double-buffered MFMA GEMM ----------------
// C[M,N] = A[M,K](bf16) @ BT[N,K](bf16)^T + bias
// EPI 1: f32 out (C0)
// EPI 2: gelu -> bf16 out (C0)
// EPI 4: fused QKV: band0 -> C0 bf16 [M][768], band1 -> C1 bf16 [M][768],
//        band2 -> C2 bf16 transposed [768][M]
// LDS layout per dbuf slot (64KB): A [256][64] bf16 (32KB) then B [256][64].
// Swizzle: physical_byte = logical_byte ^ ((row&7)<<4)  (applied on the global
// source at stage time since global_load_lds writes linearly, and on reads).
template <int EPI>
__global__ __launch_bounds__(512, 2) void gemm256(const u16* __restrict__ A,
                                                  const u16* __restrict__ BT,
                                                  const float* __restrict__ b0,
                                                  const float* __restrict__ b1,
                                                  const float* __restrict__ b2,
                                                  void* __restrict__ C0,
                                                  void* __restrict__ C1,
                                                  void* __restrict__ C2,
                                                  int M, int N, int K, int MT) {
    extern __shared__ u16 smem[];  // 2 * 65536B slots = 128KB
    const int tid = threadIdx.x;
    const int nwg = gridDim.x;
    int wg = blockIdx.x;
    // bijective XCD swizzle (all grids divisible by 8)
    wg = (wg & 7) * (nwg >> 3) + (wg >> 3);
    const int tm = wg % MT, tn = wg / MT;   // column-major raster: B-panel stays L2-hot per XCD
    const int m0 = tm * 256, n0 = tn * 256;
    const int lane = tid & 63, w = tid >> 6;
    const int wr = w >> 2, wcn = w & 3;
    const int lr = lane & 15, ls = lane >> 4;

    // staging: thread tid covers physical LDS bytes tid*16 within each 64-row
    // chunk; chunk j adds 64 rows = 8192 bytes = 4096 u16.
    const int r3 = tid >> 3, c3 = tid & 7;
    const int kswz = ((c3 ^ (r3 & 7)) << 3);   // pre-swizzled source k-offset (elements)
    const u16* gA = A + (size_t)(m0 + r3) * K + kswz;
    const u16* gB = BT + (size_t)(n0 + r3) * K + kswz;
    const size_t rstep = (size_t)64 * K;

    f32x4 acc[8][4];
#pragma unroll
    for (int i = 0; i < 8; i++)
#pragma unroll
        for (int j = 0; j < 4; j++) acc[i][j] = (f32x4){0.f, 0.f, 0.f, 0.f};

    const int NT = K >> 6;
    {   // prologue: stage tile 0 into slot 0
        u16* pA = smem + tid * 8;
        u16* pB = smem + 16384 + tid * 8;
#pragma unroll
        for (int j = 0; j < 4; j++) {
            gload16(gA + j * rstep, pA + j * 4096);
            gload16(gB + j * rstep, pB + j * 4096);
        }
    }
    __syncthreads();

    for (int t = 0; t < NT; ++t) {
        if (t + 1 < NT) {  // issue next-tile staging into the other slot (overlaps MFMA)
            const int nb = (t + 1) & 1;
            u16* pA = smem + nb * 32768 + tid * 8;
            u16* pB = smem + nb * 32768 + 16384 + tid * 8;
            const u16* sA = gA + (size_t)(t + 1) * 64;
            const u16* sB = gB + (size_t)(t + 1) * 64;
#pragma unroll
            for (int j = 0; j < 4; j++) {
                gload16(sA + j * rstep, pA + j * 4096);
                gload16(sB + j * rstep, pB + j * 4096);
            }
        }
        const u16* bufA = smem + (t & 1) * 32768 + (wr * 128 + lr) * 64;
        const u16* bufB = smem + (t & 1) * 32768 + 16384 + (wcn * 64 + lr) * 64;
#pragma unroll
        for (int ks = 0; ks < 2; ks++) {
            const int sl = ((ks << 2) | ls) ^ (lr & 7);   // swizzled 16B slot
            U16x8 af[8], bf[4];
#pragma unroll
            for (int ni = 0; ni < 4; ni++)
                bf[ni].u = *(const uint4*)(bufB + ni * 1024 + sl * 8);
#pragma unroll
            for (int mi = 0; mi < 8; mi++)
                af[mi].u = *(const uint4*)(bufA + mi * 1024 + sl * 8);
#pragma unroll
            for (int mi = 0; mi < 8; mi++)
#pragma unroll
                for (int ni = 0; ni < 4; ni++)
                    acc[mi][ni] = __builtin_amdgcn_mfma_f32_16x16x32_bf16(
                        af[mi].s, bf[ni].s, acc[mi][ni], 0, 0, 0);
        }
        __syncthreads();  // drains vmcnt(0): next tile landed; all reads of cur done
    }

    // epilogue
#pragma unroll
    for (int mi = 0; mi < 8; mi++) {
        int row0 = m0 + wr * 128 + mi * 16 + ls * 4;
#pragma unroll
        for (int ni = 0; ni < 4; ni++) {
            int col = n0 + wcn * 64 + ni * 16 + lr;
            float v[4];
            if (EPI == 4) {
                int band = col / 768;
                int colq = col - band * 768;
                const float* bp = (band == 0) ? b0 : (band == 1) ? b1 : b2;
                float bs = bp[colq];
#pragma unroll
                for (int r = 0; r < 4; r++) v[r] = acc[mi][ni][r] + bs;
                if (band == 2) {   // V^T: [feature][ROWS]
                    uint2 wv;
                    wv.x = pack2(v[0], v[1]);
                    wv.y = pack2(v[2], v[3]);
                    *reinterpret_cast<uint2*>((u16*)C2 + (size_t)colq * M + row0) = wv;
                } else {
                    u16* dst = (band == 0) ? (u16*)C0 : (u16*)C1;
#pragma unroll
                    for (int r = 0; r < 4; r++)
                        dst[(size_t)(row0 + r) * 768 + colq] = f2b(v[r]);
                }
            } else {
                float bs = b0[col];
#pragma unroll
                for (int r = 0; r < 4; r++) {
                    v[r] = acc[mi][ni][r] + bs;
                    if (EPI == 2) v[r] = 0.5f * v[r] * (1.0f + erff(v[r] * 0.70710678118654752f));
                }
                if (EPI == 1) {
#pragma unroll
                    for (int r = 0; r < 4; r++)
                        ((float*)C0)[(size_t)(row0 + r) * N + col] = v[r];
                } else {
#pragma unroll
                    for (int r = 0; r < 4; r++)
                        ((u16*)C0)[(size_t)(row0 + r) * N + col] = f2b(v[r]);
                }
            }
        }
    }
}

// ---------------- residual add + LayerNorm (writes f32 + bf16) ----------------
__global__ __launch_bounds__(256) void resid_ln(const float* __restrict__ a,
                                                const float* __restrict__ res,
                                                const float* __restrict__ g,
                                                const float* __restrict__ be,
                                                float* __restrict__ of,
                                                u16* __restrict__ ob) {
    __shared__ float red[8];
    const int row = blockIdx.x;
    const int tid = threadIdx.x;
    const size_t base = (size_t)row * 768;
    float v[3];
    float s = 0.f;
#pragma unroll
    for (int i = 0; i < 3; i++) {
        int c = tid + i * 256;
        v[i] = a[base + c] + res[base + c];
        s += v[i];
    }
#pragma unroll
    for (int off = 32; off; off >>= 1) s += __shfl_down(s, off);
    if ((tid & 63) == 0) red[tid >> 6] = s;
    __syncthreads();
    float mean = (red[0] + red[1] + red[2] + red[3]) * (1.f / 768.f);
    float q = 0.f;
#pragma unroll
    for (int i = 0; i < 3; i++) {
        float d = v[i] - mean;
        q += d * d;
    }
#pragma unroll
    for (int off = 32; off; off >>= 1) q += __shfl_down(q, off);
    if ((tid & 63) == 0) red[4 + (tid >> 6)] = q;
    __syncthreads();
    float var = (red[4] + red[5] + red[6] + red[7]) * (1.f / 768.f);
    float inv = rsqrtf(var + 1e-12f);
#pragma unroll
    for (int i = 0; i < 3; i++) {
        int c = tid + i * 256;
        float y = (v[i] - mean) * inv * g[c] + be[c];
        of[base + c] = y;
        ob[base + c] = f2b(y);
    }
}

// ---------------- halo block attention (MFMA) ----------------
__global__ __launch_bounds__(256) void attn_mfma(const u16* __restrict__ Q,
                                                 const u16* __restrict__ Kx,
                                                 const u16* __restrict__ Vt,
                                                 u16* __restrict__ Ctx) {
    __shared__ u16 sm0[128 * 104];  // P (padded stride 104); also K [192][64] swizzled
    __shared__ u16 sm1[64 * 192];   // V^T [64][192] swizzled
    u16* Ks = sm0;
    u16* Ps = sm0;
    u16* Vs = sm1;

    const int bid = blockIdx.x;
    const int h = bid % HH;
    const int n = (bid / HH) % NBLK;
    const int b = bid / (HH * NBLK);
    const int tid = threadIdx.x;
    const int lane = tid & 63, w = tid >> 6;
    const int lr = lane & 15, ls = lane >> 4;
    const int s0 = n * 128 - 32;

#pragma unroll
    for (int j = 0; j < 6; j++) {
        int r = (tid >> 3) + j * 32;
        int c = tid & 7;
        int s = min(max(s0 + r, 0), SS - 1);
        uint4 kv = *reinterpret_cast<const uint4*>(Kx + ((size_t)(b * SS + s)) * 768 + h * 64 + c * 8);
        int byteo = r * 128 + ((c * 16) ^ ((r & 7) << 4));
        *reinterpret_cast<uint4*>(Ks + (byteo >> 1)) = kv;
    }
#pragma unroll
    for (int j = 0; j < 6; j++) {
        int d = tid >> 2;
        int c = (tid & 3) + j * 4;
        int sv = min(max(s0 + c * 8, 0), SS - 8);
        uint4 vv = *reinterpret_cast<const uint4*>(Vt + ((size_t)(h * 64 + d)) * ROWS + b * SS + sv);
        int byteo = d * 384 + ((c * 16) ^ ((d & 7) << 4));
        *reinterpret_cast<uint4*>(Vs + (byteo >> 1)) = vv;
    }
    __syncthreads();

    const int qrow0 = b * SS + n * 128 + w * 32;
    U16x8 qf[2][2];
#pragma unroll
    for (int mi = 0; mi < 2; mi++)
#pragma unroll
        for (int ks = 0; ks < 2; ks++)
            qf[mi][ks].u = *reinterpret_cast<const uint4*>(
                Q + (size_t)(qrow0 + mi * 16 + lr) * 768 + h * 64 + ks * 32 + ls * 8);

    f32x4 sc[2][12];
#pragma unroll
    for (int mi = 0; mi < 2; mi++)
#pragma unroll
        for (int jt = 0; jt < 12; jt++) sc[mi][jt] = (f32x4){0.f, 0.f, 0.f, 0.f};
#pragma unroll
    for (int jt = 0; jt < 12; jt++) {
        U16x8 kf[2];
#pragma unroll
        for (int ks = 0; ks < 2; ks++) {
            int r = jt * 16 + lr;
            int byteo = r * 128 + ((ks * 64 + ls * 16) ^ ((r & 7) << 4));
            kf[ks].u = *reinterpret_cast<const uint4*>(Ks + (byteo >> 1));
        }
#pragma unroll
        for (int mi = 0; mi < 2; mi++)
#pragma unroll
            for (int ks = 0; ks < 2; ks++)
                sc[mi][jt] = __builtin_amdgcn_mfma_f32_16x16x32_bf16(
                    qf[mi][ks].s, kf[ks].s, sc[mi][jt], 0, 0, 0);
    }

    const int lo = (n == 0) ? 32 : 0;
    const int hi = (n == NBLK - 1) ? 160 : 192;
    float mx[2][4], sm[2][4], inv[2][4];
#pragma unroll
    for (int mi = 0; mi < 2; mi++)
#pragma unroll
        for (int r = 0; r < 4; r++) { mx[mi][r] = -3.0e38f; sm[mi][r] = 0.f; }
#pragma unroll
    for (int jt = 0; jt < 12; jt++) {
        int col = jt * 16 + lr;
        bool valid = (col >= lo) && (col < hi);
#pragma unroll
        for (int mi = 0; mi < 2; mi++)
#pragma unroll
            for (int r = 0; r < 4; r++) {
                float v = valid ? sc[mi][jt][r] * 0.125f : -3.0e38f;
                sc[mi][jt][r] = v;
                mx[mi][r] = fmaxf(mx[mi][r], v);
            }
    }
#pragma unroll
    for (int o = 1; o <= 8; o <<= 1)
#pragma unroll
        for (int mi = 0; mi < 2; mi++)
#pragma unroll
            for (int r = 0; r < 4; r++)
                mx[mi][r] = fmaxf(mx[mi][r], __shfl_xor(mx[mi][r], o));
#pragma unroll
    for (int jt = 0; jt < 12; jt++)
#pragma unroll
        for (int mi = 0; mi < 2; mi++)
#pragma unroll
            for (int r = 0; r < 4; r++) {
                float p = __expf(sc[mi][jt][r] - mx[mi][r]);
                sc[mi][jt][r] = p;
                sm[mi][r] += p;
            }
#pragma unroll
    for (int o = 1; o <= 8; o <<= 1)
#pragma unroll
        for (int mi = 0; mi < 2; mi++)
#pragma unroll
            for (int r = 0; r < 4; r++)
                sm[mi][r] += __shfl_xor(sm[mi][r], o);
#pragma unroll
    for (int mi = 0; mi < 2; mi++)
#pragma unroll
        for (int r = 0; r < 4; r++) inv[mi][r] = 1.0f / sm[mi][r];

    f32x4 oacc[2][4];
#pragma unroll
    for (int mi = 0; mi < 2; mi++)
#pragma unroll
        for (int dt = 0; dt < 4; dt++) oacc[mi][dt] = (f32x4){0.f, 0.f, 0.f, 0.f};
    __syncthreads();

#pragma unroll
    for (int ph = 0; ph < 2; ph++) {
#pragma unroll
        for (int jj = 0; jj < 6; jj++) {
            int jt = ph * 6 + jj;
#pragma unroll
            for (int mi = 0; mi < 2; mi++) {
                int row = w * 32 + mi * 16 + ls * 4;
#pragma unroll
                for (int r = 0; r < 4; r++)
                    Ps[(row + r) * 104 + jj * 16 + lr] = f2b(sc[mi][jt][r]);
            }
        }
        __syncthreads();
#pragma unroll
        for (int kk = 0; kk < 3; kk++) {
            U16x8 pf[2], vf[4];
#pragma unroll
            for (int mi = 0; mi < 2; mi++)
                pf[mi].u = *reinterpret_cast<const uint4*>(
                    Ps + (w * 32 + mi * 16 + lr) * 104 + kk * 32 + ls * 8);
#pragma unroll
            for (int dt = 0; dt < 4; dt++) {
                int rrow = dt * 16 + lr;
                int byteo = rrow * 384 + ((ph * 192 + kk * 64 + ls * 16) ^ ((rrow & 7) << 4));
                vf[dt].u = *reinterpret_cast<const uint4*>(Vs + (byteo >> 1));
            }
#pragma unroll
            for (int mi = 0; mi < 2; mi++)
#pragma unroll
                for (int dt = 0; dt < 4; dt++)
                    oacc[mi][dt] = __builtin_amdgcn_mfma_f32_16x16x32_bf16(
                        pf[mi].s, vf[dt].s, oacc[mi][dt], 0, 0, 0);
        }
        __syncthreads();
    }

#pragma unroll
    for (int mi = 0; mi < 2; mi++)
#pragma unroll
        for (int dt = 0; dt < 4; dt++)
#pragma unroll
            for (int r = 0; r < 4; r++) {
                float v = oacc[mi][dt][r] * inv[mi][r];
                Ctx[(size_t)(qrow0 + mi * 16 + ls * 4 + r) * 768 + h * 64 + dt * 16 + lr] = f2b(v);
            }
}

extern "C" void kernel_launch(void* const* d_in, const int* in_sizes, int n_in,
                              void* d_out, int out_size, void* d_ws, size_t ws_size,
                              hipStream_t stream) {
    (void)in_sizes; (void)n_in; (void)out_size; (void)ws_size;
    const float* x    = (const float*)d_in[0];
    const float* Wq   = (const float*)d_in[1];
    const float* bq   = (const float*)d_in[2];
    const float* Wk   = (const float*)d_in[3];
    const float* bk   = (const float*)d_in[4];
    const float* Wv   = (const float*)d_in[5];
    const float* bv   = (const float*)d_in[6];
    const float* Wo   = (const float*)d_in[7];
    const float* bo   = (const float*)d_in[8];
    const float* ln1g = (const float*)d_in[9];
    const float* ln1b = (const float*)d_in[10];
    const float* W1   = (const float*)d_in[11];
    const float* b1   = (const float*)d_in[12];
    const float* W2   = (const float*)d_in[13];
    const float* b2   = (const float*)d_in[14];
    const float* ln2g = (const float*)d_in[15];
    const float* ln2b = (const float*)d_in[16];
    float* out = (float*)d_out;

    char* ws = (char*)d_ws;
    size_t off = 0;
    auto alloc = [&](size_t bytes) -> char* {
        char* p = ws + off;
        off += (bytes + 255) & ~(size_t)255;
        return p;
    };
    u16* WqkvT = (u16*)alloc(2 * 3 * D2 * sizeof(u16));  // per layer: [Q;K;V] rows
    u16* WoT   = (u16*)alloc(2 * D2 * sizeof(u16));
    u16* W1T   = (u16*)alloc(2 * DI * sizeof(u16));
    u16* W2T   = (u16*)alloc(2 * DI * sizeof(u16));
    u16* Xb    = (u16*)alloc(AD * sizeof(u16));
    u16* RegA  = (u16*)alloc(4 * AD * sizeof(u16)); // Qb,Kb,Vt,Ctxb; reused as H1b
    float* AttnF = (float*)alloc(AD * sizeof(float));
    u16*   AttnB = (u16*)alloc(AD * sizeof(u16));
    float* H2f   = (float*)alloc(AD * sizeof(float));
    u16* Qb = RegA;
    u16* Kb = RegA + AD;
    u16* Vtb = RegA + 2 * AD;   // V^T layout: [feature][B*S]
    u16* Ctxb = RegA + 3 * AD;
    u16* H1b = RegA;

    {
        int nelem = ROWS * DD;
        cast_bf16<<<dim3(nelem / 4 / 256), dim3(256), 0, stream>>>(x, Xb, nelem);
    }
    for (int l = 0; l < 2; l++) {
        u16* base = WqkvT + (size_t)l * 3 * D2;
        cast_transpose<<<dim3(24, 24), dim3(32, 8), 0, stream>>>(Wq + l * D2, base, 768, 768);
        cast_transpose<<<dim3(24, 24), dim3(32, 8), 0, stream>>>(Wk + l * D2, base + D2, 768, 768);
        cast_transpose<<<dim3(24, 24), dim3(32, 8), 0, stream>>>(Wv + l * D2, base + 2 * D2, 768, 768);
        cast_transpose<<<dim3(24, 24), dim3(32, 8), 0, stream>>>(Wo + l * D2, WoT + l * D2, 768, 768);
        cast_transpose<<<dim3(96, 24), dim3(32, 8), 0, stream>>>(W1 + l * DI, W1T + l * DI, 768, 3072);
        cast_transpose<<<dim3(24, 96), dim3(32, 8), 0, stream>>>(W2 + l * DI, W2T + l * DI, 3072, 768);
    }

    const size_t LDSB = 131072;
    const float* xres = x;
    for (int l = 0; l < 2; l++) {
        // fused QKV: N=2304 (bands Q|K|V), V written transposed
        gemm256<4><<<dim3(64 * 9), 512, LDSB, stream>>>(
            Xb, WqkvT + (size_t)l * 3 * D2, bq + l * 768, bk + l * 768, bv + l * 768,
            Qb, Kb, Vtb, ROWS, 2304, 768, 64);
        attn_mfma<<<dim3(BB * NBLK * HH), 256, 0, stream>>>(Qb, Kb, Vtb, Ctxb);
        gemm256<1><<<dim3(64 * 3), 512, LDSB, stream>>>(
            Ctxb, WoT + l * D2, bo + l * 768, nullptr, nullptr,
            H2f, nullptr, nullptr, ROWS, 768, 768, 64);
        resid_ln<<<dim3(ROWS), 256, 0, stream>>>(H2f, xres, ln1g + l * 768, ln1b + l * 768, AttnF, AttnB);
        gemm256<2><<<dim3(64 * 12), 512, LDSB, stream>>>(
            AttnB, W1T + l * DI, b1 + l * 3072, nullptr, nullptr,
            H1b, nullptr, nullptr, ROWS, 3072, 768, 64);
        gemm256<1><<<dim3(64 * 3), 512, LDSB, stream>>>(
            H1b, W2T + l * DI, b2 + l * 768, nullptr, nullptr,
            H2f, nullptr, nullptr, ROWS, 768, 3072, 64);
        float* outl = out + (size_t)l * AD;
        resid_ln<<<dim3(ROWS), 256, 0, stream>>>(H2f, AttnF, ln2g + l * 768, ln2b + l * 768, outl, Xb);
        xres = outl;
    }
}

// Round 5
// 1076.733 us; speedup vs baseline: 1.1358x; 1.1358x over previous
//
#include <hip/hip_runtime.h>
#include <hip/hip_bf16.h>

typedef unsigned short u16;
typedef unsigned int u32;

static const int DD = 768;
static const int SS = 2048;
static const int BB = 8;
static const int HH = 12;
static const int NBLK = 16;   // S / 128
static const int ROWS = BB * SS;          // 16384
static const size_t AD = (size_t)ROWS * DD;   // activation element count
static const size_t D2 = (size_t)DD * DD;
static const size_t DI = (size_t)DD * 3072;

typedef __attribute__((ext_vector_type(8))) short short8;
typedef __attribute__((ext_vector_type(4))) float f32x4;

union U16x8 { uint4 u; short8 s; };

__device__ __forceinline__ float bl(u32 u) { return __uint_as_float(u << 16); }
__device__ __forceinline__ float bh(u32 u) { return __uint_as_float(u & 0xffff0000u); }
__device__ __forceinline__ u16 f2b(float f) {
    u32 u = __float_as_uint(f);
    u += 0x7fffu + ((u >> 16) & 1u);
    return (u16)(u >> 16);
}
__device__ __forceinline__ u32 pack2(float lo, float hi) {
    return (u32)f2b(lo) | ((u32)f2b(hi) << 16);
}

// async global->LDS, 16B per lane (dest is wave-uniform base + lane*16)
__device__ __forceinline__ void gload16(const u16* g, u16* l) {
    __builtin_amdgcn_global_load_lds(
        (const __attribute__((address_space(1))) void*)g,
        (__attribute__((address_space(3))) void*)l, 16, 0, 0);
}

// ---------------- elementwise f32 -> bf16 cast ----------------
__global__ __launch_bounds__(256) void cast_bf16(const float* __restrict__ x,
                                                 u16* __restrict__ xb, int n) {
    int i = (blockIdx.x * 256 + threadIdx.x) * 4;
    if (i < n) {
        float4 v = *reinterpret_cast<const float4*>(x + i);
        uint2 p;
        p.x = pack2(v.x, v.y);
        p.y = pack2(v.z, v.w);
        *reinterpret_cast<uint2*>(xb + i) = p;
    }
}

// ---------------- cast + transpose: W[K,N] f32 -> WT[N,K] bf16 ----------------
__global__ __launch_bounds__(256) void cast_transpose(const float* __restrict__ W,
                                                      u16* __restrict__ WT,
                                                      int K, int N) {
    __shared__ float tile[32][33];
    int bx = blockIdx.x;  // along N
    int by = blockIdx.y;  // along K
    int tx = threadIdx.x; // 0..31
    int ty = threadIdx.y; // 0..7
#pragma unroll
    for (int i = 0; i < 4; i++) {
        int kr = by * 32 + ty + i * 8;
        tile[ty + i * 8][tx] = W[(size_t)kr * N + bx * 32 + tx];
    }
    __syncthreads();
#pragma unroll
    for (int i = 0; i < 4; i++) {
        int nr = bx * 32 + ty + i * 8;
        WT[(size_t)nr * K + by * 32 + tx] = f2b(tile[tx][ty + i * 8]);
    }
}

// ---------------- 128x128 double-buffered MFMA GEMM (2 blocks/CU) ----------------
// C[M,N] = A[M,K](bf16) @ BT[N,K](bf16)^T + bias
// EPI 1: f32 out (C0);  2: gelu -> bf16 out (C0)
// EPI 4: fused QKV: band0 -> C0 bf16 [M][768], band1 -> C1 bf16 [M][768],
//        band2 -> C2 bf16 transposed [768][M]
// LDS per dbuf slot (32KB): A [128 rows][128B] then B [128 rows][128B].
// Swizzle: physical 16B-slot = logical_slot ^ (row&7); applied by pre-swizzling
// the global source k-offset at stage time (LDS dest stays linear for
// global_load_lds) and XORing the slot index on ds_read (rule #21).
template <int EPI>
__global__ __launch_bounds__(256, 2) void gemm128(const u16* __restrict__ A,
                                                  const u16* __restrict__ BT,
                                                  const float* __restrict__ b0,
                                                  const float* __restrict__ b1,
                                                  const float* __restrict__ b2,
                                                  void* __restrict__ C0,
                                                  void* __restrict__ C1,
                                                  void* __restrict__ C2,
                                                  int M, int N, int K, int MT) {
    extern __shared__ u16 smem[];  // 2 slots x 16384 u16 (32KB) = 64KB
    const int tid = threadIdx.x;
    const int nwg = gridDim.x;
    int wg = blockIdx.x;
    // bijective XCD swizzle (all grids divisible by 8)
    wg = (wg & 7) * (nwg >> 3) + (wg >> 3);
    const int tm = wg % MT, tn = wg / MT;   // column-major raster: B-panel L2-hot
    const int m0 = tm * 128, n0 = tn * 128;
    const int lane = tid & 63, w = tid >> 6;
    const int wr = w >> 1, wc = w & 1;
    const int lr = lane & 15, ls = lane >> 4;

    // staging: chunk j covers rows [j*32, j*32+32); thread: row r3=tid>>3,
    // physical slot c3=tid&7 -> source k-slot (c3 ^ (r3&7)).
    const int r3 = tid >> 3, c3 = tid & 7;
    const int kswz = ((c3 ^ (r3 & 7)) << 3);   // pre-swizzled source k-offset (elems)
    const u16* gA = A + (size_t)(m0 + r3) * K + kswz;
    const u16* gB = BT + (size_t)(n0 + r3) * K + kswz;
    const size_t rstep = (size_t)32 * K;       // 32 rows per chunk

    f32x4 acc[4][4];
#pragma unroll
    for (int i = 0; i < 4; i++)
#pragma unroll
        for (int j = 0; j < 4; j++) acc[i][j] = (f32x4){0.f, 0.f, 0.f, 0.f};

    const int NT = K >> 6;
    {   // prologue: stage tile 0 into slot 0
        u16* pA = smem + tid * 8;
        u16* pB = smem + 8192 + tid * 8;
#pragma unroll
        for (int j = 0; j < 4; j++) {
            gload16(gA + j * rstep, pA + j * 2048);
            gload16(gB + j * rstep, pB + j * 2048);
        }
    }
    __syncthreads();

    for (int t = 0; t < NT; ++t) {
        if (t + 1 < NT) {  // prefetch next tile into other slot (overlaps MFMA)
            const int nb = (t + 1) & 1;
            u16* pA = smem + nb * 16384 + tid * 8;
            u16* pB = smem + nb * 16384 + 8192 + tid * 8;
            const u16* sA = gA + (size_t)(t + 1) * 64;
            const u16* sB = gB + (size_t)(t + 1) * 64;
#pragma unroll
            for (int j = 0; j < 4; j++) {
                gload16(sA + j * rstep, pA + j * 2048);
                gload16(sB + j * rstep, pB + j * 2048);
            }
        }
        const u16* bufA = smem + (t & 1) * 16384 + (wr * 64 + lr) * 64;
        const u16* bufB = smem + (t & 1) * 16384 + 8192 + (wc * 64 + lr) * 64;
#pragma unroll
        for (int ks = 0; ks < 2; ks++) {
            const int sl = ((ks << 2) | ls) ^ (lr & 7);   // swizzled 16B slot
            U16x8 af[4], bf[4];
#pragma unroll
            for (int ni = 0; ni < 4; ni++)
                bf[ni].u = *(const uint4*)(bufB + ni * 1024 + sl * 8);
#pragma unroll
            for (int mi = 0; mi < 4; mi++)
                af[mi].u = *(const uint4*)(bufA + mi * 1024 + sl * 8);
#pragma unroll
            for (int mi = 0; mi < 4; mi++)
#pragma unroll
                for (int ni = 0; ni < 4; ni++)
                    acc[mi][ni] = __builtin_amdgcn_mfma_f32_16x16x32_bf16(
                        af[mi].s, bf[ni].s, acc[mi][ni], 0, 0, 0);
        }
        __syncthreads();  // drains vmcnt(0): next tile landed; cur reads done
    }

    // epilogue
#pragma unroll
    for (int mi = 0; mi < 4; mi++) {
        int row0 = m0 + wr * 64 + mi * 16 + ls * 4;
#pragma unroll
        for (int ni = 0; ni < 4; ni++) {
            int col = n0 + wc * 64 + ni * 16 + lr;
            float v[4];
            if (EPI == 4) {
                int band = col / 768;
                int colq = col - band * 768;
                const float* bp = (band == 0) ? b0 : (band == 1) ? b1 : b2;
                float bs = bp[colq];
#pragma unroll
                for (int r = 0; r < 4; r++) v[r] = acc[mi][ni][r] + bs;
                if (band == 2) {   // V^T: [feature][ROWS]
                    uint2 wv;
                    wv.x = pack2(v[0], v[1]);
                    wv.y = pack2(v[2], v[3]);
                    *reinterpret_cast<uint2*>((u16*)C2 + (size_t)colq * M + row0) = wv;
                } else {
                    u16* dst = (band == 0) ? (u16*)C0 : (u16*)C1;
#pragma unroll
                    for (int r = 0; r < 4; r++)
                        dst[(size_t)(row0 + r) * 768 + colq] = f2b(v[r]);
                }
            } else {
                float bs = b0[col];
#pragma unroll
                for (int r = 0; r < 4; r++) {
                    v[r] = acc[mi][ni][r] + bs;
                    if (EPI == 2) v[r] = 0.5f * v[r] * (1.0f + erff(v[r] * 0.70710678118654752f));
                }
                if (EPI == 1) {
#pragma unroll
                    for (int r = 0; r < 4; r++)
                        ((float*)C0)[(size_t)(row0 + r) * N + col] = v[r];
                } else {
#pragma unroll
                    for (int r = 0; r < 4; r++)
                        ((u16*)C0)[(size_t)(row0 + r) * N + col] = f2b(v[r]);
                }
            }
        }
    }
}

// ---------------- residual add + LayerNorm (writes f32 + bf16) ----------------
__global__ __launch_bounds__(256) void resid_ln(const float* __restrict__ a,
                                                const float* __restrict__ res,
                                                const float* __restrict__ g,
                                                const float* __restrict__ be,
                                                float* __restrict__ of,
                                                u16* __restrict__ ob) {
    __shared__ float red[8];
    const int row = blockIdx.x;
    const int tid = threadIdx.x;
    const size_t base = (size_t)row * 768;
    float v[3];
    float s = 0.f;
#pragma unroll
    for (int i = 0; i < 3; i++) {
        int c = tid + i * 256;
        v[i] = a[base + c] + res[base + c];
        s += v[i];
    }
#pragma unroll
    for (int off = 32; off; off >>= 1) s += __shfl_down(s, off);
    if ((tid & 63) == 0) red[tid >> 6] = s;
    __syncthreads();
    float mean = (red[0] + red[1] + red[2] + red[3]) * (1.f / 768.f);
    float q = 0.f;
#pragma unroll
    for (int i = 0; i < 3; i++) {
        float d = v[i] - mean;
        q += d * d;
    }
#pragma unroll
    for (int off = 32; off; off >>= 1) q += __shfl_down(q, off);
    if ((tid & 63) == 0) red[4 + (tid >> 6)] = q;
    __syncthreads();
    float var = (red[4] + red[5] + red[6] + red[7]) * (1.f / 768.f);
    float inv = rsqrtf(var + 1e-12f);
#pragma unroll
    for (int i = 0; i < 3; i++) {
        int c = tid + i * 256;
        float y = (v[i] - mean) * inv * g[c] + be[c];
        of[base + c] = y;
        ob[base + c] = f2b(y);
    }
}

// ---------------- halo block attention (MFMA) ----------------
__global__ __launch_bounds__(256) void attn_mfma(const u16* __restrict__ Q,
                                                 const u16* __restrict__ Kx,
                                                 const u16* __restrict__ Vt,
                                                 u16* __restrict__ Ctx) {
    __shared__ u16 sm0[128 * 104];  // P (padded stride 104); also K [192][64] swizzled
    __shared__ u16 sm1[64 * 192];   // V^T [64][192] swizzled
    u16* Ks = sm0;
    u16* Ps = sm0;
    u16* Vs = sm1;

    const int bid = blockIdx.x;
    const int h = bid % HH;
    const int n = (bid / HH) % NBLK;
    const int b = bid / (HH * NBLK);
    const int tid = threadIdx.x;
    const int lane = tid & 63, w = tid >> 6;
    const int lr = lane & 15, ls = lane >> 4;
    const int s0 = n * 128 - 32;

#pragma unroll
    for (int j = 0; j < 6; j++) {
        int r = (tid >> 3) + j * 32;
        int c = tid & 7;
        int s = min(max(s0 + r, 0), SS - 1);
        uint4 kv = *reinterpret_cast<const uint4*>(Kx + ((size_t)(b * SS + s)) * 768 + h * 64 + c * 8);
        int byteo = r * 128 + ((c * 16) ^ ((r & 7) << 4));
        *reinterpret_cast<uint4*>(Ks + (byteo >> 1)) = kv;
    }
#pragma unroll
    for (int j = 0; j < 6; j++) {
        int d = tid >> 2;
        int c = (tid & 3) + j * 4;
        int sv = min(max(s0 + c * 8, 0), SS - 8);
        uint4 vv = *reinterpret_cast<const uint4*>(Vt + ((size_t)(h * 64 + d)) * ROWS + b * SS + sv);
        int byteo = d * 384 + ((c * 16) ^ ((d & 7) << 4));
        *reinterpret_cast<uint4*>(Vs + (byteo >> 1)) = vv;
    }
    __syncthreads();

    const int qrow0 = b * SS + n * 128 + w * 32;
    U16x8 qf[2][2];
#pragma unroll
    for (int mi = 0; mi < 2; mi++)
#pragma unroll
        for (int ks = 0; ks < 2; ks++)
            qf[mi][ks].u = *reinterpret_cast<const uint4*>(
                Q + (size_t)(qrow0 + mi * 16 + lr) * 768 + h * 64 + ks * 32 + ls * 8);

    f32x4 sc[2][12];
#pragma unroll
    for (int mi = 0; mi < 2; mi++)
#pragma unroll
        for (int jt = 0; jt < 12; jt++) sc[mi][jt] = (f32x4){0.f, 0.f, 0.f, 0.f};
#pragma unroll
    for (int jt = 0; jt < 12; jt++) {
        U16x8 kf[2];
#pragma unroll
        for (int ks = 0; ks < 2; ks++) {
            int r = jt * 16 + lr;
            int byteo = r * 128 + ((ks * 64 + ls * 16) ^ ((r & 7) << 4));
            kf[ks].u = *reinterpret_cast<const uint4*>(Ks + (byteo >> 1));
        }
#pragma unroll
        for (int mi = 0; mi < 2; mi++)
#pragma unroll
            for (int ks = 0; ks < 2; ks++)
                sc[mi][jt] = __builtin_amdgcn_mfma_f32_16x16x32_bf16(
                    qf[mi][ks].s, kf[ks].s, sc[mi][jt], 0, 0, 0);
    }

    const int lo = (n == 0) ? 32 : 0;
    const int hi = (n == NBLK - 1) ? 160 : 192;
    float mx[2][4], sm[2][4], inv[2][4];
#pragma unroll
    for (int mi = 0; mi < 2; mi++)
#pragma unroll
        for (int r = 0; r < 4; r++) { mx[mi][r] = -3.0e38f; sm[mi][r] = 0.f; }
#pragma unroll
    for (int jt = 0; jt < 12; jt++) {
        int col = jt * 16 + lr;
        bool valid = (col >= lo) && (col < hi);
#pragma unroll
        for (int mi = 0; mi < 2; mi++)
#pragma unroll
            for (int r = 0; r < 4; r++) {
                float v = valid ? sc[mi][jt][r] * 0.125f : -3.0e38f;
                sc[mi][jt][r] = v;
                mx[mi][r] = fmaxf(mx[mi][r], v);
            }
    }
#pragma unroll
    for (int o = 1; o <= 8; o <<= 1)
#pragma unroll
        for (int mi = 0; mi < 2; mi++)
#pragma unroll
            for (int r = 0; r < 4; r++)
                mx[mi][r] = fmaxf(mx[mi][r], __shfl_xor(mx[mi][r], o));
#pragma unroll
    for (int jt = 0; jt < 12; jt++)
#pragma unroll
        for (int mi = 0; mi < 2; mi++)
#pragma unroll
            for (int r = 0; r < 4; r++) {
                float p = __expf(sc[mi][jt][r] - mx[mi][r]);
                sc[mi][jt][r] = p;
                sm[mi][r] += p;
            }
#pragma unroll
    for (int o = 1; o <= 8; o <<= 1)
#pragma unroll
        for (int mi = 0; mi < 2; mi++)
#pragma unroll
            for (int r = 0; r < 4; r++)
                sm[mi][r] += __shfl_xor(sm[mi][r], o);
#pragma unroll
    for (int mi = 0; mi < 2; mi++)
#pragma unroll
        for (int r = 0; r < 4; r++) inv[mi][r] = 1.0f / sm[mi][r];

    f32x4 oacc[2][4];
#pragma unroll
    for (int mi = 0; mi < 2; mi++)
#pragma unroll
        for (int dt = 0; dt < 4; dt++) oacc[mi][dt] = (f32x4){0.f, 0.f, 0.f, 0.f};
    __syncthreads();

#pragma unroll
    for (int ph = 0; ph < 2; ph++) {
#pragma unroll
        for (int jj = 0; jj < 6; jj++) {
            int jt = ph * 6 + jj;
#pragma unroll
            for (int mi = 0; mi < 2; mi++) {
                int row = w * 32 + mi * 16 + ls * 4;
#pragma unroll
                for (int r = 0; r < 4; r++)
                    Ps[(row + r) * 104 + jj * 16 + lr] = f2b(sc[mi][jt][r]);
            }
        }
        __syncthreads();
#pragma unroll
        for (int kk = 0; kk < 3; kk++) {
            U16x8 pf[2], vf[4];
#pragma unroll
            for (int mi = 0; mi < 2; mi++)
                pf[mi].u = *reinterpret_cast<const uint4*>(
                    Ps + (w * 32 + mi * 16 + lr) * 104 + kk * 32 + ls * 8);
#pragma unroll
            for (int dt = 0; dt < 4; dt++) {
                int rrow = dt * 16 + lr;
                int byteo = rrow * 384 + ((ph * 192 + kk * 64 + ls * 16) ^ ((rrow & 7) << 4));
                vf[dt].u = *reinterpret_cast<const uint4*>(Vs + (byteo >> 1));
            }
#pragma unroll
            for (int mi = 0; mi < 2; mi++)
#pragma unroll
                for (int dt = 0; dt < 4; dt++)
                    oacc[mi][dt] = __builtin_amdgcn_mfma_f32_16x16x32_bf16(
                        pf[mi].s, vf[dt].s, oacc[mi][dt], 0, 0, 0);
        }
        __syncthreads();
    }

#pragma unroll
    for (int mi = 0; mi < 2; mi++)
#pragma unroll
        for (int dt = 0; dt < 4; dt++)
#pragma unroll
            for (int r = 0; r < 4; r++) {
                float v = oacc[mi][dt][r] * inv[mi][r];
                Ctx[(size_t)(qrow0 + mi * 16 + ls * 4 + r) * 768 + h * 64 + dt * 16 + lr] = f2b(v);
            }
}

extern "C" void kernel_launch(void* const* d_in, const int* in_sizes, int n_in,
                              void* d_out, int out_size, void* d_ws, size_t ws_size,
                              hipStream_t stream) {
    (void)in_sizes; (void)n_in; (void)out_size; (void)ws_size;
    const float* x    = (const float*)d_in[0];
    const float* Wq   = (const float*)d_in[1];
    const float* bq   = (const float*)d_in[2];
    const float* Wk   = (const float*)d_in[3];
    const float* bk   = (const float*)d_in[4];
    const float* Wv   = (const float*)d_in[5];
    const float* bv   = (const float*)d_in[6];
    const float* Wo   = (const float*)d_in[7];
    const float* bo   = (const float*)d_in[8];
    const float* ln1g = (const float*)d_in[9];
    const float* ln1b = (const float*)d_in[10];
    const float* W1   = (const float*)d_in[11];
    const float* b1   = (const float*)d_in[12];
    const float* W2   = (const float*)d_in[13];
    const float* b2   = (const float*)d_in[14];
    const float* ln2g = (const float*)d_in[15];
    const float* ln2b = (const float*)d_in[16];
    float* out = (float*)d_out;

    char* ws = (char*)d_ws;
    size_t off = 0;
    auto alloc = [&](size_t bytes) -> char* {
        char* p = ws + off;
        off += (bytes + 255) & ~(size_t)255;
        return p;
    };
    u16* WqkvT = (u16*)alloc(2 * 3 * D2 * sizeof(u16));  // per layer: [Q;K;V] rows
    u16* WoT   = (u16*)alloc(2 * D2 * sizeof(u16));
    u16* W1T   = (u16*)alloc(2 * DI * sizeof(u16));
    u16* W2T   = (u16*)alloc(2 * DI * sizeof(u16));
    u16* Xb    = (u16*)alloc(AD * sizeof(u16));
    u16* RegA  = (u16*)alloc(4 * AD * sizeof(u16)); // Qb,Kb,Vt,Ctxb; reused as H1b
    float* AttnF = (float*)alloc(AD * sizeof(float));
    u16*   AttnB = (u16*)alloc(AD * sizeof(u16));
    float* H2f   = (float*)alloc(AD * sizeof(float));
    u16* Qb = RegA;
    u16* Kb = RegA + AD;
    u16* Vtb = RegA + 2 * AD;   // V^T layout: [feature][B*S]
    u16* Ctxb = RegA + 3 * AD;
    u16* H1b = RegA;

    {
        int nelem = ROWS * DD;
        cast_bf16<<<dim3(nelem / 4 / 256), dim3(256), 0, stream>>>(x, Xb, nelem);
    }
    for (int l = 0; l < 2; l++) {
        u16* base = WqkvT + (size_t)l * 3 * D2;
        cast_transpose<<<dim3(24, 24), dim3(32, 8), 0, stream>>>(Wq + l * D2, base, 768, 768);
        cast_transpose<<<dim3(24, 24), dim3(32, 8), 0, stream>>>(Wk + l * D2, base + D2, 768, 768);
        cast_transpose<<<dim3(24, 24), dim3(32, 8), 0, stream>>>(Wv + l * D2, base + 2 * D2, 768, 768);
        cast_transpose<<<dim3(24, 24), dim3(32, 8), 0, stream>>>(Wo + l * D2, WoT + l * D2, 768, 768);
        cast_transpose<<<dim3(96, 24), dim3(32, 8), 0, stream>>>(W1 + l * DI, W1T + l * DI, 768, 3072);
        cast_transpose<<<dim3(24, 96), dim3(32, 8), 0, stream>>>(W2 + l * DI, W2T + l * DI, 3072, 768);
    }

    const size_t LDSB = 65536;
    const float* xres = x;
    for (int l = 0; l < 2; l++) {
        // fused QKV: N=2304 (bands Q|K|V), V written transposed
        gemm128<4><<<dim3(128 * 18), 256, LDSB, stream>>>(
            Xb, WqkvT + (size_t)l * 3 * D2, bq + l * 768, bk + l * 768, bv + l * 768,
            Qb, Kb, Vtb, ROWS, 2304, 768, 128);
        attn_mfma<<<dim3(BB * NBLK * HH), 256, 0, stream>>>(Qb, Kb, Vtb, Ctxb);
        gemm128<1><<<dim3(128 * 6), 256, LDSB, stream>>>(
            Ctxb, WoT + l * D2, bo + l * 768, nullptr, nullptr,
            H2f, nullptr, nullptr, ROWS, 768, 768, 128);
        resid_ln<<<dim3(ROWS), 256, 0, stream>>>(H2f, xres, ln1g + l * 768, ln1b + l * 768, AttnF, AttnB);
        gemm128<2><<<dim3(128 * 24), 256, LDSB, stream>>>(
            AttnB, W1T + l * DI, b1 + l * 3072, nullptr, nullptr,
            H1b, nullptr, nullptr, ROWS, 3072, 768, 128);
        gemm128<1><<<dim3(128 * 6), 256, LDSB, stream>>>(
            H1b, W2T + l * DI, b2 + l * 768, nullptr, nullptr,
            H2f, nullptr, nullptr, ROWS, 768, 3072, 128);
        float* outl = out + (size_t)l * AD;
        resid_ln<<<dim3(ROWS), 256, 0, stream>>>(H2f, AttnF, ln2g + l * 768, ln2b + l * 768, outl, Xb);
        xres = outl;
    }
}

// Round 6
// 925.571 us; speedup vs baseline: 1.3213x; 1.1633x over previous
//
#include <hip/hip_runtime.h>
#include <hip/hip_bf16.h>

typedef unsigned short u16;
typedef unsigned int u32;

static const int DD = 768;
static const int SS = 2048;
static const int BB = 8;
static const int HH = 12;
static const int NBLK = 16;   // S / 128
static const int ROWS = BB * SS;          // 16384
static const size_t AD = (size_t)ROWS * DD;   // activation element count
static const size_t D2 = (size_t)DD * DD;
static const size_t DI = (size_t)DD * 3072;

typedef __attribute__((ext_vector_type(8))) short short8;
typedef __attribute__((ext_vector_type(4))) float f32x4;

union U16x8 { uint4 u; short8 s; };

__device__ __forceinline__ float bl(u32 u) { return __uint_as_float(u << 16); }
__device__ __forceinline__ float bh(u32 u) { return __uint_as_float(u & 0xffff0000u); }
__device__ __forceinline__ u16 f2b(float f) {
    u32 u = __float_as_uint(f);
    u += 0x7fffu + ((u >> 16) & 1u);
    return (u16)(u >> 16);
}
__device__ __forceinline__ u32 pack2(float lo, float hi) {
    return (u32)f2b(lo) | ((u32)f2b(hi) << 16);
}

// async global->LDS, 16B per lane (dest is wave-uniform base + lane*16)
__device__ __forceinline__ void gload16(const u16* g, u16* l) {
    __builtin_amdgcn_global_load_lds(
        (const __attribute__((address_space(1))) void*)g,
        (__attribute__((address_space(3))) void*)l, 16, 0, 0);
}

// ---------------- elementwise f32 -> bf16 cast ----------------
__global__ __launch_bounds__(256) void cast_bf16(const float* __restrict__ x,
                                                 u16* __restrict__ xb, int n) {
    int i = (blockIdx.x * 256 + threadIdx.x) * 4;
    if (i < n) {
        float4 v = *reinterpret_cast<const float4*>(x + i);
        uint2 p;
        p.x = pack2(v.x, v.y);
        p.y = pack2(v.z, v.w);
        *reinterpret_cast<uint2*>(xb + i) = p;
    }
}

// ---------------- cast + transpose: W[K,N] f32 -> WT[N,K] bf16 ----------------
__global__ __launch_bounds__(256) void cast_transpose(const float* __restrict__ W,
                                                      u16* __restrict__ WT,
                                                      int K, int N) {
    __shared__ float tile[32][33];
    int bx = blockIdx.x;  // along N
    int by = blockIdx.y;  // along K
    int tx = threadIdx.x; // 0..31
    int ty = threadIdx.y; // 0..7
#pragma unroll
    for (int i = 0; i < 4; i++) {
        int kr = by * 32 + ty + i * 8;
        tile[ty + i * 8][tx] = W[(size_t)kr * N + bx * 32 + tx];
    }
    __syncthreads();
#pragma unroll
    for (int i = 0; i < 4; i++) {
        int nr = bx * 32 + ty + i * 8;
        WT[(size_t)nr * K + by * 32 + tx] = f2b(tile[tx][ty + i * 8]);
    }
}

// ---------------- 128x128 MFMA GEMM, BK=32 double-buffer, ~5 blocks/CU ----------------
// C[M,N] = A[M,K](bf16) @ BT[N,K](bf16)^T + bias
// EPI 1: f32 out (C0);  2: gelu -> bf16 out (C0)
// EPI 4: fused QKV: band0 -> C0 bf16 [M][768], band1 -> C1 bf16 [M][768],
//        band2 -> C2 bf16 transposed [768][M]
// Raster: row-major (tn fastest) so consecutive wg share the A M-panel
// (activations read ~once; small weight panels re-read via L2/L3).
// LDS per slot (16KB): A [128 rows][64B] then B [128 rows][64B]; dbuf = 32KB.
// Swizzle (rule #21, both sides): 16B-slot phys = logical ^ (row&3); applied by
// pre-swizzling the global source k-offset (LDS dest stays linear for
// global_load_lds) and XORing the slot index on ds_read. Min 2-way = free.
template <int EPI>
__global__ __launch_bounds__(256) void gemm128(const u16* __restrict__ A,
                                               const u16* __restrict__ BT,
                                               const float* __restrict__ b0,
                                               const float* __restrict__ b1,
                                               const float* __restrict__ b2,
                                               void* __restrict__ C0,
                                               void* __restrict__ C1,
                                               void* __restrict__ C2,
                                               int M, int N, int K, int NTN) {
    extern __shared__ u16 smem[];  // 2 slots x 8192 u16 (16KB) = 32KB
    const int tid = threadIdx.x;
    const int nwg = gridDim.x;
    int wg = blockIdx.x;
    // chunked bijective XCD swizzle (all grids divisible by 8): XCD x owns
    // contiguous wg range -> A M-panels partitioned across XCDs.
    wg = (wg & 7) * (nwg >> 3) + (wg >> 3);
    const int tn = wg % NTN, tm = wg / NTN;   // row-major: A-panel stays hot
    const int m0 = tm * 128, n0 = tn * 128;
    const int lane = tid & 63, w = tid >> 6;
    const int wr = w >> 1, wc = w & 1;
    const int lr = lane & 15, ls = lane >> 4;

    // staging: chunk j covers 64 rows; thread: row r3=tid>>2 in chunk, phys
    // slot c2=tid&3 -> source k-slot (c2 ^ (r3&3)).
    const int r3 = tid >> 2, c2 = tid & 3;
    const int kswz = ((c2 ^ (r3 & 3)) << 3);   // pre-swizzled source k-offset (elems)
    const u16* gA = A + (size_t)(m0 + r3) * K + kswz;
    const u16* gB = BT + (size_t)(n0 + r3) * K + kswz;
    const size_t rstep = (size_t)64 * K;       // 64 rows per chunk

    f32x4 acc[4][4];
#pragma unroll
    for (int i = 0; i < 4; i++)
#pragma unroll
        for (int j = 0; j < 4; j++) acc[i][j] = (f32x4){0.f, 0.f, 0.f, 0.f};

    const int NT = K >> 5;
    {   // prologue: stage K-step 0 into slot 0
        u16* pA = smem + tid * 8;
        u16* pB = smem + 4096 + tid * 8;
#pragma unroll
        for (int j = 0; j < 2; j++) {
            gload16(gA + j * rstep, pA + j * 2048);
            gload16(gB + j * rstep, pB + j * 2048);
        }
    }
    __syncthreads();

    for (int t = 0; t < NT; ++t) {
        if (t + 1 < NT) {  // prefetch next K-step into other slot (overlaps MFMA)
            const int nb = (t + 1) & 1;
            u16* pA = smem + nb * 8192 + tid * 8;
            u16* pB = smem + nb * 8192 + 4096 + tid * 8;
            const u16* sA = gA + (size_t)(t + 1) * 32;
            const u16* sB = gB + (size_t)(t + 1) * 32;
#pragma unroll
            for (int j = 0; j < 2; j++) {
                gload16(sA + j * rstep, pA + j * 2048);
                gload16(sB + j * rstep, pB + j * 2048);
            }
        }
        const u16* bufA = smem + (t & 1) * 8192 + (wr * 64 + lr) * 32;
        const u16* bufB = smem + (t & 1) * 8192 + 4096 + (wc * 64 + lr) * 32;
        const int sl = ls ^ (lr & 3);   // swizzled 16B slot
        U16x8 af[4], bf[4];
#pragma unroll
        for (int ni = 0; ni < 4; ni++)
            bf[ni].u = *(const uint4*)(bufB + ni * 512 + sl * 8);
#pragma unroll
        for (int mi = 0; mi < 4; mi++)
            af[mi].u = *(const uint4*)(bufA + mi * 512 + sl * 8);
#pragma unroll
        for (int mi = 0; mi < 4; mi++)
#pragma unroll
            for (int ni = 0; ni < 4; ni++)
                acc[mi][ni] = __builtin_amdgcn_mfma_f32_16x16x32_bf16(
                    af[mi].s, bf[ni].s, acc[mi][ni], 0, 0, 0);
        __syncthreads();  // drains vmcnt(0): next step landed; cur reads done
    }

    // epilogue
#pragma unroll
    for (int mi = 0; mi < 4; mi++) {
        int row0 = m0 + wr * 64 + mi * 16 + ls * 4;
#pragma unroll
        for (int ni = 0; ni < 4; ni++) {
            int col = n0 + wc * 64 + ni * 16 + lr;
            float v[4];
            if (EPI == 4) {
                int band = col / 768;
                int colq = col - band * 768;
                const float* bp = (band == 0) ? b0 : (band == 1) ? b1 : b2;
                float bs = bp[colq];
#pragma unroll
                for (int r = 0; r < 4; r++) v[r] = acc[mi][ni][r] + bs;
                if (band == 2) {   // V^T: [feature][ROWS]
                    uint2 wv;
                    wv.x = pack2(v[0], v[1]);
                    wv.y = pack2(v[2], v[3]);
                    *reinterpret_cast<uint2*>((u16*)C2 + (size_t)colq * M + row0) = wv;
                } else {
                    u16* dst = (band == 0) ? (u16*)C0 : (u16*)C1;
#pragma unroll
                    for (int r = 0; r < 4; r++)
                        dst[(size_t)(row0 + r) * 768 + colq] = f2b(v[r]);
                }
            } else {
                float bs = b0[col];
#pragma unroll
                for (int r = 0; r < 4; r++) {
                    v[r] = acc[mi][ni][r] + bs;
                    if (EPI == 2) v[r] = 0.5f * v[r] * (1.0f + erff(v[r] * 0.70710678118654752f));
                }
                if (EPI == 1) {
#pragma unroll
                    for (int r = 0; r < 4; r++)
                        ((float*)C0)[(size_t)(row0 + r) * N + col] = v[r];
                } else {
#pragma unroll
                    for (int r = 0; r < 4; r++)
                        ((u16*)C0)[(size_t)(row0 + r) * N + col] = f2b(v[r]);
                }
            }
        }
    }
}

// ---------------- residual add + LayerNorm (writes f32 + bf16) ----------------
__global__ __launch_bounds__(256) void resid_ln(const float* __restrict__ a,
                                                const float* __restrict__ res,
                                                const float* __restrict__ g,
                                                const float* __restrict__ be,
                                                float* __restrict__ of,
                                                u16* __restrict__ ob) {
    __shared__ float red[8];
    const int row = blockIdx.x;
    const int tid = threadIdx.x;
    const size_t base = (size_t)row * 768;
    float v[3];
    float s = 0.f;
#pragma unroll
    for (int i = 0; i < 3; i++) {
        int c = tid + i * 256;
        v[i] = a[base + c] + res[base + c];
        s += v[i];
    }
#pragma unroll
    for (int off = 32; off; off >>= 1) s += __shfl_down(s, off);
    if ((tid & 63) == 0) red[tid >> 6] = s;
    __syncthreads();
    float mean = (red[0] + red[1] + red[2] + red[3]) * (1.f / 768.f);
    float q = 0.f;
#pragma unroll
    for (int i = 0; i < 3; i++) {
        float d = v[i] - mean;
        q += d * d;
    }
#pragma unroll
    for (int off = 32; off; off >>= 1) q += __shfl_down(q, off);
    if ((tid & 63) == 0) red[4 + (tid >> 6)] = q;
    __syncthreads();
    float var = (red[4] + red[5] + red[6] + red[7]) * (1.f / 768.f);
    float inv = rsqrtf(var + 1e-12f);
#pragma unroll
    for (int i = 0; i < 3; i++) {
        int c = tid + i * 256;
        float y = (v[i] - mean) * inv * g[c] + be[c];
        of[base + c] = y;
        ob[base + c] = f2b(y);
    }
}

// ---------------- halo block attention (MFMA) ----------------
__global__ __launch_bounds__(256) void attn_mfma(const u16* __restrict__ Q,
                                                 const u16* __restrict__ Kx,
                                                 const u16* __restrict__ Vt,
                                                 u16* __restrict__ Ctx) {
    __shared__ u16 sm0[128 * 104];  // P (padded stride 104); also K [192][64] swizzled
    __shared__ u16 sm1[64 * 192];   // V^T [64][192] swizzled
    u16* Ks = sm0;
    u16* Ps = sm0;
    u16* Vs = sm1;

    const int bid = blockIdx.x;
    const int h = bid % HH;
    const int n = (bid / HH) % NBLK;
    const int b = bid / (HH * NBLK);
    const int tid = threadIdx.x;
    const int lane = tid & 63, w = tid >> 6;
    const int lr = lane & 15, ls = lane >> 4;
    const int s0 = n * 128 - 32;

#pragma unroll
    for (int j = 0; j < 6; j++) {
        int r = (tid >> 3) + j * 32;
        int c = tid & 7;
        int s = min(max(s0 + r, 0), SS - 1);
        uint4 kv = *reinterpret_cast<const uint4*>(Kx + ((size_t)(b * SS + s)) * 768 + h * 64 + c * 8);
        int byteo = r * 128 + ((c * 16) ^ ((r & 7) << 4));
        *reinterpret_cast<uint4*>(Ks + (byteo >> 1)) = kv;
    }
#pragma unroll
    for (int j = 0; j < 6; j++) {
        int d = tid >> 2;
        int c = (tid & 3) + j * 4;
        int sv = min(max(s0 + c * 8, 0), SS - 8);
        uint4 vv = *reinterpret_cast<const uint4*>(Vt + ((size_t)(h * 64 + d)) * ROWS + b * SS + sv);
        int byteo = d * 384 + ((c * 16) ^ ((d & 7) << 4));
        *reinterpret_cast<uint4*>(Vs + (byteo >> 1)) = vv;
    }
    __syncthreads();

    const int qrow0 = b * SS + n * 128 + w * 32;
    U16x8 qf[2][2];
#pragma unroll
    for (int mi = 0; mi < 2; mi++)
#pragma unroll
        for (int ks = 0; ks < 2; ks++)
            qf[mi][ks].u = *reinterpret_cast<const uint4*>(
                Q + (size_t)(qrow0 + mi * 16 + lr) * 768 + h * 64 + ks * 32 + ls * 8);

    f32x4 sc[2][12];
#pragma unroll
    for (int mi = 0; mi < 2; mi++)
#pragma unroll
        for (int jt = 0; jt < 12; jt++) sc[mi][jt] = (f32x4){0.f, 0.f, 0.f, 0.f};
#pragma unroll
    for (int jt = 0; jt < 12; jt++) {
        U16x8 kf[2];
#pragma unroll
        for (int ks = 0; ks < 2; ks++) {
            int r = jt * 16 + lr;
            int byteo = r * 128 + ((ks * 64 + ls * 16) ^ ((r & 7) << 4));
            kf[ks].u = *reinterpret_cast<const uint4*>(Ks + (byteo >> 1));
        }
#pragma unroll
        for (int mi = 0; mi < 2; mi++)
#pragma unroll
            for (int ks = 0; ks < 2; ks++)
                sc[mi][jt] = __builtin_amdgcn_mfma_f32_16x16x32_bf16(
                    qf[mi][ks].s, kf[ks].s, sc[mi][jt], 0, 0, 0);
    }

    const int lo = (n == 0) ? 32 : 0;
    const int hi = (n == NBLK - 1) ? 160 : 192;
    float mx[2][4], sm[2][4], inv[2][4];
#pragma unroll
    for (int mi = 0; mi < 2; mi++)
#pragma unroll
        for (int r = 0; r < 4; r++) { mx[mi][r] = -3.0e38f; sm[mi][r] = 0.f; }
#pragma unroll
    for (int jt = 0; jt < 12; jt++) {
        int col = jt * 16 + lr;
        bool valid = (col >= lo) && (col < hi);
#pragma unroll
        for (int mi = 0; mi < 2; mi++)
#pragma unroll
            for (int r = 0; r < 4; r++) {
                float v = valid ? sc[mi][jt][r] * 0.125f : -3.0e38f;
                sc[mi][jt][r] = v;
                mx[mi][r] = fmaxf(mx[mi][r], v);
            }
    }
#pragma unroll
    for (int o = 1; o <= 8; o <<= 1)
#pragma unroll
        for (int mi = 0; mi < 2; mi++)
#pragma unroll
            for (int r = 0; r < 4; r++)
                mx[mi][r] = fmaxf(mx[mi][r], __shfl_xor(mx[mi][r], o));
#pragma unroll
    for (int jt = 0; jt < 12; jt++)
#pragma unroll
        for (int mi = 0; mi < 2; mi++)
#pragma unroll
            for (int r = 0; r < 4; r++) {
                float p = __expf(sc[mi][jt][r] - mx[mi][r]);
                sc[mi][jt][r] = p;
                sm[mi][r] += p;
            }
#pragma unroll
    for (int o = 1; o <= 8; o <<= 1)
#pragma unroll
        for (int mi = 0; mi < 2; mi++)
#pragma unroll
            for (int r = 0; r < 4; r++)
                sm[mi][r] += __shfl_xor(sm[mi][r], o);
#pragma unroll
    for (int mi = 0; mi < 2; mi++)
#pragma unroll
        for (int r = 0; r < 4; r++) inv[mi][r] = 1.0f / sm[mi][r];

    f32x4 oacc[2][4];
#pragma unroll
    for (int mi = 0; mi < 2; mi++)
#pragma unroll
        for (int dt = 0; dt < 4; dt++) oacc[mi][dt] = (f32x4){0.f, 0.f, 0.f, 0.f};
    __syncthreads();

#pragma unroll
    for (int ph = 0; ph < 2; ph++) {
#pragma unroll
        for (int jj = 0; jj < 6; jj++) {
            int jt = ph * 6 + jj;
#pragma unroll
            for (int mi = 0; mi < 2; mi++) {
                int row = w * 32 + mi * 16 + ls * 4;
#pragma unroll
                for (int r = 0; r < 4; r++)
                    Ps[(row + r) * 104 + jj * 16 + lr] = f2b(sc[mi][jt][r]);
            }
        }
        __syncthreads();
#pragma unroll
        for (int kk = 0; kk < 3; kk++) {
            U16x8 pf[2], vf[4];
#pragma unroll
            for (int mi = 0; mi < 2; mi++)
                pf[mi].u = *reinterpret_cast<const uint4*>(
                    Ps + (w * 32 + mi * 16 + lr) * 104 + kk * 32 + ls * 8);
#pragma unroll
            for (int dt = 0; dt < 4; dt++) {
                int rrow = dt * 16 + lr;
                int byteo = rrow * 384 + ((ph * 192 + kk * 64 + ls * 16) ^ ((rrow & 7) << 4));
                vf[dt].u = *reinterpret_cast<const uint4*>(Vs + (byteo >> 1));
            }
#pragma unroll
            for (int mi = 0; mi < 2; mi++)
#pragma unroll
                for (int dt = 0; dt < 4; dt++)
                    oacc[mi][dt] = __builtin_amdgcn_mfma_f32_16x16x32_bf16(
                        pf[mi].s, vf[dt].s, oacc[mi][dt], 0, 0, 0);
        }
        __syncthreads();
    }

#pragma unroll
    for (int mi = 0; mi < 2; mi++)
#pragma unroll
        for (int dt = 0; dt < 4; dt++)
#pragma unroll
            for (int r = 0; r < 4; r++) {
                float v = oacc[mi][dt][r] * inv[mi][r];
                Ctx[(size_t)(qrow0 + mi * 16 + ls * 4 + r) * 768 + h * 64 + dt * 16 + lr] = f2b(v);
            }
}

extern "C" void kernel_launch(void* const* d_in, const int* in_sizes, int n_in,
                              void* d_out, int out_size, void* d_ws, size_t ws_size,
                              hipStream_t stream) {
    (void)in_sizes; (void)n_in; (void)out_size; (void)ws_size;
    const float* x    = (const float*)d_in[0];
    const float* Wq   = (const float*)d_in[1];
    const float* bq   = (const float*)d_in[2];
    const float* Wk   = (const float*)d_in[3];
    const float* bk   = (const float*)d_in[4];
    const float* Wv   = (const float*)d_in[5];
    const float* bv   = (const float*)d_in[6];
    const float* Wo   = (const float*)d_in[7];
    const float* bo   = (const float*)d_in[8];
    const float* ln1g = (const float*)d_in[9];
    const float* ln1b = (const float*)d_in[10];
    const float* W1   = (const float*)d_in[11];
    const float* b1   = (const float*)d_in[12];
    const float* W2   = (const float*)d_in[13];
    const float* b2   = (const float*)d_in[14];
    const float* ln2g = (const float*)d_in[15];
    const float* ln2b = (const float*)d_in[16];
    float* out = (float*)d_out;

    char* ws = (char*)d_ws;
    size_t off = 0;
    auto alloc = [&](size_t bytes) -> char* {
        char* p = ws + off;
        off += (bytes + 255) & ~(size_t)255;
        return p;
    };
    u16* WqkvT = (u16*)alloc(2 * 3 * D2 * sizeof(u16));  // per layer: [Q;K;V] rows
    u16* WoT   = (u16*)alloc(2 * D2 * sizeof(u16));
    u16* W1T   = (u16*)alloc(2 * DI * sizeof(u16));
    u16* W2T   = (u16*)alloc(2 * DI * sizeof(u16));
    u16* Xb    = (u16*)alloc(AD * sizeof(u16));
    u16* RegA  = (u16*)alloc(4 * AD * sizeof(u16)); // Qb,Kb,Vt,Ctxb; reused as H1b
    float* AttnF = (float*)alloc(AD * sizeof(float));
    u16*   AttnB = (u16*)alloc(AD * sizeof(u16));
    float* H2f   = (float*)alloc(AD * sizeof(float));
    u16* Qb = RegA;
    u16* Kb = RegA + AD;
    u16* Vtb = RegA + 2 * AD;   // V^T layout: [feature][B*S]
    u16* Ctxb = RegA + 3 * AD;
    u16* H1b = RegA;

    {
        int nelem = ROWS * DD;
        cast_bf16<<<dim3(nelem / 4 / 256), dim3(256), 0, stream>>>(x, Xb, nelem);
    }
    for (int l = 0; l < 2; l++) {
        u16* base = WqkvT + (size_t)l * 3 * D2;
        cast_transpose<<<dim3(24, 24), dim3(32, 8), 0, stream>>>(Wq + l * D2, base, 768, 768);
        cast_transpose<<<dim3(24, 24), dim3(32, 8), 0, stream>>>(Wk + l * D2, base + D2, 768, 768);
        cast_transpose<<<dim3(24, 24), dim3(32, 8), 0, stream>>>(Wv + l * D2, base + 2 * D2, 768, 768);
        cast_transpose<<<dim3(24, 24), dim3(32, 8), 0, stream>>>(Wo + l * D2, WoT + l * D2, 768, 768);
        cast_transpose<<<dim3(96, 24), dim3(32, 8), 0, stream>>>(W1 + l * DI, W1T + l * DI, 768, 3072);
        cast_transpose<<<dim3(24, 96), dim3(32, 8), 0, stream>>>(W2 + l * DI, W2T + l * DI, 3072, 768);
    }

    const size_t LDSB = 32768;
    const float* xres = x;
    for (int l = 0; l < 2; l++) {
        // fused QKV: N=2304 (bands Q|K|V), V written transposed
        gemm128<4><<<dim3(128 * 18), 256, LDSB, stream>>>(
            Xb, WqkvT + (size_t)l * 3 * D2, bq + l * 768, bk + l * 768, bv + l * 768,
            Qb, Kb, Vtb, ROWS, 2304, 768, 18);
        attn_mfma<<<dim3(BB * NBLK * HH), 256, 0, stream>>>(Qb, Kb, Vtb, Ctxb);
        gemm128<1><<<dim3(128 * 6), 256, LDSB, stream>>>(
            Ctxb, WoT + l * D2, bo + l * 768, nullptr, nullptr,
            H2f, nullptr, nullptr, ROWS, 768, 768, 6);
        resid_ln<<<dim3(ROWS), 256, 0, stream>>>(H2f, xres, ln1g + l * 768, ln1b + l * 768, AttnF, AttnB);
        gemm128<2><<<dim3(128 * 24), 256, LDSB, stream>>>(
            AttnB, W1T + l * DI, b1 + l * 3072, nullptr, nullptr,
            H1b, nullptr, nullptr, ROWS, 3072, 768, 24);
        gemm128<1><<<dim3(128 * 6), 256, LDSB, stream>>>(
            H1b, W2T + l * DI, b2 + l * 768, nullptr, nullptr,
            H2f, nullptr, nullptr, ROWS, 768, 3072, 6);
        float* outl = out + (size_t)l * AD;
        resid_ln<<<dim3(ROWS), 256, 0, stream>>>(H2f, AttnF, ln2g + l * 768, ln2b + l * 768, outl, Xb);
        xres = outl;
    }
}

// Round 7
// 908.270 us; speedup vs baseline: 1.3464x; 1.0190x over previous
//
#include <hip/hip_runtime.h>
#include <hip/hip_bf16.h>

typedef unsigned short u16;
typedef unsigned int u32;

static const int DD = 768;
static const int SS = 2048;
static const int BB = 8;
static const int HH = 12;
static const int NBLK = 16;   // S / 128
static const int ROWS = BB * SS;          // 16384
static const size_t AD = (size_t)ROWS * DD;   // activation element count
static const size_t D2 = (size_t)DD * DD;
static const size_t DI = (size_t)DD * 3072;

typedef __attribute__((ext_vector_type(8))) short short8;
typedef __attribute__((ext_vector_type(4))) float f32x4;

union U16x8 { uint4 u; short8 s; };

__device__ __forceinline__ float bl(u32 u) { return __uint_as_float(u << 16); }
__device__ __forceinline__ float bh(u32 u) { return __uint_as_float(u & 0xffff0000u); }
__device__ __forceinline__ u16 f2b(float f) {
    u32 u = __float_as_uint(f);
    u += 0x7fffu + ((u >> 16) & 1u);
    return (u16)(u >> 16);
}
__device__ __forceinline__ u32 pack2(float lo, float hi) {
    return (u32)f2b(lo) | ((u32)f2b(hi) << 16);
}

// async global->LDS, 16B per lane (dest is wave-uniform base + lane*16)
__device__ __forceinline__ void gload16(const u16* g, u16* l) {
    __builtin_amdgcn_global_load_lds(
        (const __attribute__((address_space(1))) void*)g,
        (__attribute__((address_space(3))) void*)l, 16, 0, 0);
}

// ---------------- elementwise f32 -> bf16 cast ----------------
__global__ __launch_bounds__(256) void cast_bf16(const float* __restrict__ x,
                                                 u16* __restrict__ xb, int n) {
    int i = (blockIdx.x * 256 + threadIdx.x) * 4;
    if (i < n) {
        float4 v = *reinterpret_cast<const float4*>(x + i);
        uint2 p;
        p.x = pack2(v.x, v.y);
        p.y = pack2(v.z, v.w);
        *reinterpret_cast<uint2*>(xb + i) = p;
    }
}

// ---------------- cast + transpose: W[K,N] f32 -> WT[N,K] bf16 ----------------
__global__ __launch_bounds__(256) void cast_transpose(const float* __restrict__ W,
                                                      u16* __restrict__ WT,
                                                      int K, int N) {
    __shared__ float tile[32][33];
    int bx = blockIdx.x;  // along N
    int by = blockIdx.y;  // along K
    int tx = threadIdx.x; // 0..31
    int ty = threadIdx.y; // 0..7
#pragma unroll
    for (int i = 0; i < 4; i++) {
        int kr = by * 32 + ty + i * 8;
        tile[ty + i * 8][tx] = W[(size_t)kr * N + bx * 32 + tx];
    }
    __syncthreads();
#pragma unroll
    for (int i = 0; i < 4; i++) {
        int nr = bx * 32 + ty + i * 8;
        WT[(size_t)nr * K + by * 32 + tx] = f2b(tile[tx][ty + i * 8]);
    }
}

// ---------------- 128x128 MFMA GEMM, counted-vmcnt 3-deep ring (T3/T4) ----------
// C[M,N] = A[M,K](bf16) @ BT[N,K](bf16)^T + bias
// EPI 1: f32 out; 2: gelu->bf16 out; 4: fused QKV (band2 -> C2 transposed).
// Ring: 3 slots x (A[128r][64B] + B[128r][64B]) = 48KB -> 3 blocks/CU.
// Each thread issues exactly 4 global_load_lds per tile, in tile order, so
// s_waitcnt vmcnt(8) == "tile t landed, t+1/t+2 in flight". Loads are NEVER
// drained to 0 in the main loop (T4); raw s_barrier (no implicit vmcnt(0)).
// Swizzle (both-sides, rule #21): phys 16B-slot = logical ^ (row&3), applied by
// pre-swizzling the global source k-offset; read XORs the slot the same way.
// Requires NT = K/32 >= 4 (all call sites: 24 or 96).
template <int EPI>
__global__ __launch_bounds__(256) void gemm128(const u16* __restrict__ A,
                                               const u16* __restrict__ BT,
                                               const float* __restrict__ b0,
                                               const float* __restrict__ b1,
                                               const float* __restrict__ b2,
                                               void* __restrict__ C0,
                                               void* __restrict__ C1,
                                               void* __restrict__ C2,
                                               int M, int N, int K, int NTN) {
    extern __shared__ u16 smem[];  // 3 slots x 8192 u16 (16KB) = 48KB
    const int tid = threadIdx.x;
    const int nwg = gridDim.x;
    int wg = blockIdx.x;
    // chunked bijective XCD swizzle (all grids divisible by 8)
    wg = (wg & 7) * (nwg >> 3) + (wg >> 3);
    const int tn = wg % NTN, tm = wg / NTN;   // row-major: A M-panel stays hot
    const int m0 = tm * 128, n0 = tn * 128;
    const int lane = tid & 63, w = tid >> 6;
    const int wr = w >> 1, wc = w & 1;
    const int lr = lane & 15, ls = lane >> 4;

    // staging: chunk j covers 64 rows; thread: row r3=tid>>2 in chunk, phys
    // slot c2=tid&3 -> source k-slot (c2 ^ (r3&3)).
    const int r3 = tid >> 2, c2 = tid & 3;
    const int kswz = ((c2 ^ (r3 & 3)) << 3);   // pre-swizzled source k-offset
    const u16* gA = A + (size_t)(m0 + r3) * K + kswz;
    const u16* gB = BT + (size_t)(n0 + r3) * K + kswz;
    const size_t rstep = (size_t)64 * K;       // 64 rows per chunk

    f32x4 acc[4][4];
#pragma unroll
    for (int i = 0; i < 4; i++)
#pragma unroll
        for (int j = 0; j < 4; j++) acc[i][j] = (f32x4){0.f, 0.f, 0.f, 0.f};

    const int NT = K >> 5;
    // prologue: stage tiles 0,1,2 into slots 0,1,2 (4 loads per tile, in order)
#pragma unroll
    for (int p = 0; p < 3; ++p) {
        u16* pA = smem + p * 8192 + tid * 8;
        u16* pB = smem + p * 8192 + 4096 + tid * 8;
        const u16* sA = gA + (size_t)p * 32;
        const u16* sB = gB + (size_t)p * 32;
        gload16(sA, pA);
        gload16(sA + rstep, pA + 2048);
        gload16(sB, pB);
        gload16(sB + rstep, pB + 2048);
    }

    int slot = 0;
    for (int t = 0; t < NT; ++t) {
        // T4: wait for tile t only; keep t+1/t+2 in flight (4 loads each)
        if (t + 2 < NT)      asm volatile("s_waitcnt vmcnt(8)" ::: "memory");
        else if (t + 1 < NT) asm volatile("s_waitcnt vmcnt(4)" ::: "memory");
        else                 asm volatile("s_waitcnt vmcnt(0)" ::: "memory");
        __builtin_amdgcn_s_barrier();          // all waves' tile-t loads landed
        __builtin_amdgcn_sched_barrier(0);

        const u16* bufA = smem + slot * 8192 + (wr * 64 + lr) * 32;
        const u16* bufB = smem + slot * 8192 + 4096 + (wc * 64 + lr) * 32;
        const int sl = ls ^ (lr & 3);          // swizzled 16B slot
        U16x8 af[4], bf[4];
#pragma unroll
        for (int ni = 0; ni < 4; ni++)
            bf[ni].u = *(const uint4*)(bufB + ni * 512 + sl * 8);
#pragma unroll
        for (int mi = 0; mi < 4; mi++)
            af[mi].u = *(const uint4*)(bufA + mi * 512 + sl * 8);
        asm volatile("s_waitcnt lgkmcnt(0)" ::: "memory");
        __builtin_amdgcn_sched_barrier(0);     // rule #18: pin MFMA below wait
        __builtin_amdgcn_s_barrier();          // all waves done reading slot
        __builtin_amdgcn_sched_barrier(0);

        if (t + 3 < NT) {                      // stage tile t+3 into freed slot
            u16* pA = smem + slot * 8192 + tid * 8;
            u16* pB = smem + slot * 8192 + 4096 + tid * 8;
            const u16* sA = gA + (size_t)(t + 3) * 32;
            const u16* sB = gB + (size_t)(t + 3) * 32;
            gload16(sA, pA);
            gload16(sA + rstep, pA + 2048);
            gload16(sB, pB);
            gload16(sB + rstep, pB + 2048);
        }
        __builtin_amdgcn_sched_barrier(0);

        __builtin_amdgcn_s_setprio(1);
#pragma unroll
        for (int mi = 0; mi < 4; mi++)
#pragma unroll
            for (int ni = 0; ni < 4; ni++)
                acc[mi][ni] = __builtin_amdgcn_mfma_f32_16x16x32_bf16(
                    af[mi].s, bf[ni].s, acc[mi][ni], 0, 0, 0);
        __builtin_amdgcn_s_setprio(0);
        slot = (slot == 2) ? 0 : slot + 1;
    }

    // epilogue
#pragma unroll
    for (int mi = 0; mi < 4; mi++) {
        int row0 = m0 + wr * 64 + mi * 16 + ls * 4;
#pragma unroll
        for (int ni = 0; ni < 4; ni++) {
            int col = n0 + wc * 64 + ni * 16 + lr;
            float v[4];
            if (EPI == 4) {
                int band = col / 768;
                int colq = col - band * 768;
                const float* bp = (band == 0) ? b0 : (band == 1) ? b1 : b2;
                float bs = bp[colq];
#pragma unroll
                for (int r = 0; r < 4; r++) v[r] = acc[mi][ni][r] + bs;
                if (band == 2) {   // V^T: [feature][ROWS]
                    uint2 wv;
                    wv.x = pack2(v[0], v[1]);
                    wv.y = pack2(v[2], v[3]);
                    *reinterpret_cast<uint2*>((u16*)C2 + (size_t)colq * M + row0) = wv;
                } else {
                    u16* dst = (band == 0) ? (u16*)C0 : (u16*)C1;
#pragma unroll
                    for (int r = 0; r < 4; r++)
                        dst[(size_t)(row0 + r) * 768 + colq] = f2b(v[r]);
                }
            } else {
                float bs = b0[col];
#pragma unroll
                for (int r = 0; r < 4; r++) {
                    v[r] = acc[mi][ni][r] + bs;
                    if (EPI == 2) v[r] = 0.5f * v[r] * (1.0f + erff(v[r] * 0.70710678118654752f));
                }
                if (EPI == 1) {
#pragma unroll
                    for (int r = 0; r < 4; r++)
                        ((float*)C0)[(size_t)(row0 + r) * N + col] = v[r];
                } else {
#pragma unroll
                    for (int r = 0; r < 4; r++)
                        ((u16*)C0)[(size_t)(row0 + r) * N + col] = f2b(v[r]);
                }
            }
        }
    }
}

// ---------------- residual add + LayerNorm (writes f32 + bf16) ----------------
__global__ __launch_bounds__(256) void resid_ln(const float* __restrict__ a,
                                                const float* __restrict__ res,
                                                const float* __restrict__ g,
                                                const float* __restrict__ be,
                                                float* __restrict__ of,
                                                u16* __restrict__ ob) {
    __shared__ float red[8];
    const int row = blockIdx.x;
    const int tid = threadIdx.x;
    const size_t base = (size_t)row * 768;
    float v[3];
    float s = 0.f;
#pragma unroll
    for (int i = 0; i < 3; i++) {
        int c = tid + i * 256;
        v[i] = a[base + c] + res[base + c];
        s += v[i];
    }
#pragma unroll
    for (int off = 32; off; off >>= 1) s += __shfl_down(s, off);
    if ((tid & 63) == 0) red[tid >> 6] = s;
    __syncthreads();
    float mean = (red[0] + red[1] + red[2] + red[3]) * (1.f / 768.f);
    float q = 0.f;
#pragma unroll
    for (int i = 0; i < 3; i++) {
        float d = v[i] - mean;
        q += d * d;
    }
#pragma unroll
    for (int off = 32; off; off >>= 1) q += __shfl_down(q, off);
    if ((tid & 63) == 0) red[4 + (tid >> 6)] = q;
    __syncthreads();
    float var = (red[4] + red[5] + red[6] + red[7]) * (1.f / 768.f);
    float inv = rsqrtf(var + 1e-12f);
#pragma unroll
    for (int i = 0; i < 3; i++) {
        int c = tid + i * 256;
        float y = (v[i] - mean) * inv * g[c] + be[c];
        of[base + c] = y;
        ob[base + c] = f2b(y);
    }
}

// ---------------- halo block attention (MFMA) ----------------
__global__ __launch_bounds__(256) void attn_mfma(const u16* __restrict__ Q,
                                                 const u16* __restrict__ Kx,
                                                 const u16* __restrict__ Vt,
                                                 u16* __restrict__ Ctx) {
    __shared__ u16 sm0[128 * 104];  // P (padded stride 104); also K [192][64] swizzled
    __shared__ u16 sm1[64 * 192];   // V^T [64][192] swizzled
    u16* Ks = sm0;
    u16* Ps = sm0;
    u16* Vs = sm1;

    const int bid = blockIdx.x;
    const int h = bid % HH;
    const int n = (bid / HH) % NBLK;
    const int b = bid / (HH * NBLK);
    const int tid = threadIdx.x;
    const int lane = tid & 63, w = tid >> 6;
    const int lr = lane & 15, ls = lane >> 4;
    const int s0 = n * 128 - 32;

#pragma unroll
    for (int j = 0; j < 6; j++) {
        int r = (tid >> 3) + j * 32;
        int c = tid & 7;
        int s = min(max(s0 + r, 0), SS - 1);
        uint4 kv = *reinterpret_cast<const uint4*>(Kx + ((size_t)(b * SS + s)) * 768 + h * 64 + c * 8);
        int byteo = r * 128 + ((c * 16) ^ ((r & 7) << 4));
        *reinterpret_cast<uint4*>(Ks + (byteo >> 1)) = kv;
    }
#pragma unroll
    for (int j = 0; j < 6; j++) {
        int d = tid >> 2;
        int c = (tid & 3) + j * 4;
        int sv = min(max(s0 + c * 8, 0), SS - 8);
        uint4 vv = *reinterpret_cast<const uint4*>(Vt + ((size_t)(h * 64 + d)) * ROWS + b * SS + sv);
        int byteo = d * 384 + ((c * 16) ^ ((d & 7) << 4));
        *reinterpret_cast<uint4*>(Vs + (byteo >> 1)) = vv;
    }
    __syncthreads();

    const int qrow0 = b * SS + n * 128 + w * 32;
    U16x8 qf[2][2];
#pragma unroll
    for (int mi = 0; mi < 2; mi++)
#pragma unroll
        for (int ks = 0; ks < 2; ks++)
            qf[mi][ks].u = *reinterpret_cast<const uint4*>(
                Q + (size_t)(qrow0 + mi * 16 + lr) * 768 + h * 64 + ks * 32 + ls * 8);

    f32x4 sc[2][12];
#pragma unroll
    for (int mi = 0; mi < 2; mi++)
#pragma unroll
        for (int jt = 0; jt < 12; jt++) sc[mi][jt] = (f32x4){0.f, 0.f, 0.f, 0.f};
#pragma unroll
    for (int jt = 0; jt < 12; jt++) {
        U16x8 kf[2];
#pragma unroll
        for (int ks = 0; ks < 2; ks++) {
            int r = jt * 16 + lr;
            int byteo = r * 128 + ((ks * 64 + ls * 16) ^ ((r & 7) << 4));
            kf[ks].u = *reinterpret_cast<const uint4*>(Ks + (byteo >> 1));
        }
#pragma unroll
        for (int mi = 0; mi < 2; mi++)
#pragma unroll
            for (int ks = 0; ks < 2; ks++)
                sc[mi][jt] = __builtin_amdgcn_mfma_f32_16x16x32_bf16(
                    qf[mi][ks].s, kf[ks].s, sc[mi][jt], 0, 0, 0);
    }

    const int lo = (n == 0) ? 32 : 0;
    const int hi = (n == NBLK - 1) ? 160 : 192;
    float mx[2][4], sm[2][4], inv[2][4];
#pragma unroll
    for (int mi = 0; mi < 2; mi++)
#pragma unroll
        for (int r = 0; r < 4; r++) { mx[mi][r] = -3.0e38f; sm[mi][r] = 0.f; }
#pragma unroll
    for (int jt = 0; jt < 12; jt++) {
        int col = jt * 16 + lr;
        bool valid = (col >= lo) && (col < hi);
#pragma unroll
        for (int mi = 0; mi < 2; mi++)
#pragma unroll
            for (int r = 0; r < 4; r++) {
                float v = valid ? sc[mi][jt][r] * 0.125f : -3.0e38f;
                sc[mi][jt][r] = v;
                mx[mi][r] = fmaxf(mx[mi][r], v);
            }
    }
#pragma unroll
    for (int o = 1; o <= 8; o <<= 1)
#pragma unroll
        for (int mi = 0; mi < 2; mi++)
#pragma unroll
            for (int r = 0; r < 4; r++)
                mx[mi][r] = fmaxf(mx[mi][r], __shfl_xor(mx[mi][r], o));
#pragma unroll
    for (int jt = 0; jt < 12; jt++)
#pragma unroll
        for (int mi = 0; mi < 2; mi++)
#pragma unroll
            for (int r = 0; r < 4; r++) {
                float p = __expf(sc[mi][jt][r] - mx[mi][r]);
                sc[mi][jt][r] = p;
                sm[mi][r] += p;
            }
#pragma unroll
    for (int o = 1; o <= 8; o <<= 1)
#pragma unroll
        for (int mi = 0; mi < 2; mi++)
#pragma unroll
            for (int r = 0; r < 4; r++)
                sm[mi][r] += __shfl_xor(sm[mi][r], o);
#pragma unroll
    for (int mi = 0; mi < 2; mi++)
#pragma unroll
        for (int r = 0; r < 4; r++) inv[mi][r] = 1.0f / sm[mi][r];

    f32x4 oacc[2][4];
#pragma unroll
    for (int mi = 0; mi < 2; mi++)
#pragma unroll
        for (int dt = 0; dt < 4; dt++) oacc[mi][dt] = (f32x4){0.f, 0.f, 0.f, 0.f};
    __syncthreads();

#pragma unroll
    for (int ph = 0; ph < 2; ph++) {
#pragma unroll
        for (int jj = 0; jj < 6; jj++) {
            int jt = ph * 6 + jj;
#pragma unroll
            for (int mi = 0; mi < 2; mi++) {
                int row = w * 32 + mi * 16 + ls * 4;
#pragma unroll
                for (int r = 0; r < 4; r++)
                    Ps[(row + r) * 104 + jj * 16 + lr] = f2b(sc[mi][jt][r]);
            }
        }
        __syncthreads();
#pragma unroll
        for (int kk = 0; kk < 3; kk++) {
            U16x8 pf[2], vf[4];
#pragma unroll
            for (int mi = 0; mi < 2; mi++)
                pf[mi].u = *reinterpret_cast<const uint4*>(
                    Ps + (w * 32 + mi * 16 + lr) * 104 + kk * 32 + ls * 8);
#pragma unroll
            for (int dt = 0; dt < 4; dt++) {
                int rrow = dt * 16 + lr;
                int byteo = rrow * 384 + ((ph * 192 + kk * 64 + ls * 16) ^ ((rrow & 7) << 4));
                vf[dt].u = *reinterpret_cast<const uint4*>(Vs + (byteo >> 1));
            }
#pragma unroll
            for (int mi = 0; mi < 2; mi++)
#pragma unroll
                for (int dt = 0; dt < 4; dt++)
                    oacc[mi][dt] = __builtin_amdgcn_mfma_f32_16x16x32_bf16(
                        pf[mi].s, vf[dt].s, oacc[mi][dt], 0, 0, 0);
        }
        __syncthreads();
    }

#pragma unroll
    for (int mi = 0; mi < 2; mi++)
#pragma unroll
        for (int dt = 0; dt < 4; dt++)
#pragma unroll
            for (int r = 0; r < 4; r++) {
                float v = oacc[mi][dt][r] * inv[mi][r];
                Ctx[(size_t)(qrow0 + mi * 16 + ls * 4 + r) * 768 + h * 64 + dt * 16 + lr] = f2b(v);
            }
}

extern "C" void kernel_launch(void* const* d_in, const int* in_sizes, int n_in,
                              void* d_out, int out_size, void* d_ws, size_t ws_size,
                              hipStream_t stream) {
    (void)in_sizes; (void)n_in; (void)out_size; (void)ws_size;
    const float* x    = (const float*)d_in[0];
    const float* Wq   = (const float*)d_in[1];
    const float* bq   = (const float*)d_in[2];
    const float* Wk   = (const float*)d_in[3];
    const float* bk   = (const float*)d_in[4];
    const float* Wv   = (const float*)d_in[5];
    const float* bv   = (const float*)d_in[6];
    const float* Wo   = (const float*)d_in[7];
    const float* bo   = (const float*)d_in[8];
    const float* ln1g = (const float*)d_in[9];
    const float* ln1b = (const float*)d_in[10];
    const float* W1   = (const float*)d_in[11];
    const float* b1   = (const float*)d_in[12];
    const float* W2   = (const float*)d_in[13];
    const float* b2   = (const float*)d_in[14];
    const float* ln2g = (const float*)d_in[15];
    const float* ln2b = (const float*)d_in[16];
    float* out = (float*)d_out;

    char* ws = (char*)d_ws;
    size_t off = 0;
    auto alloc = [&](size_t bytes) -> char* {
        char* p = ws + off;
        off += (bytes + 255) & ~(size_t)255;
        return p;
    };
    u16* WqkvT = (u16*)alloc(2 * 3 * D2 * sizeof(u16));  // per layer: [Q;K;V] rows
    u16* WoT   = (u16*)alloc(2 * D2 * sizeof(u16));
    u16* W1T   = (u16*)alloc(2 * DI * sizeof(u16));
    u16* W2T   = (u16*)alloc(2 * DI * sizeof(u16));
    u16* Xb    = (u16*)alloc(AD * sizeof(u16));
    u16* RegA  = (u16*)alloc(4 * AD * sizeof(u16)); // Qb,Kb,Vt,Ctxb; reused as H1b
    float* AttnF = (float*)alloc(AD * sizeof(float));
    u16*   AttnB = (u16*)alloc(AD * sizeof(u16));
    float* H2f   = (float*)alloc(AD * sizeof(float));
    u16* Qb = RegA;
    u16* Kb = RegA + AD;
    u16* Vtb = RegA + 2 * AD;   // V^T layout: [feature][B*S]
    u16* Ctxb = RegA + 3 * AD;
    u16* H1b = RegA;

    {
        int nelem = ROWS * DD;
        cast_bf16<<<dim3(nelem / 4 / 256), dim3(256), 0, stream>>>(x, Xb, nelem);
    }
    for (int l = 0; l < 2; l++) {
        u16* base = WqkvT + (size_t)l * 3 * D2;
        cast_transpose<<<dim3(24, 24), dim3(32, 8), 0, stream>>>(Wq + l * D2, base, 768, 768);
        cast_transpose<<<dim3(24, 24), dim3(32, 8), 0, stream>>>(Wk + l * D2, base + D2, 768, 768);
        cast_transpose<<<dim3(24, 24), dim3(32, 8), 0, stream>>>(Wv + l * D2, base + 2 * D2, 768, 768);
        cast_transpose<<<dim3(24, 24), dim3(32, 8), 0, stream>>>(Wo + l * D2, WoT + l * D2, 768, 768);
        cast_transpose<<<dim3(96, 24), dim3(32, 8), 0, stream>>>(W1 + l * DI, W1T + l * DI, 768, 3072);
        cast_transpose<<<dim3(24, 96), dim3(32, 8), 0, stream>>>(W2 + l * DI, W2T + l * DI, 3072, 768);
    }

    const size_t LDSB = 49152;   // 3-slot ring
    const float* xres = x;
    for (int l = 0; l < 2; l++) {
        // fused QKV: N=2304 (bands Q|K|V), V written transposed
        gemm128<4><<<dim3(128 * 18), 256, LDSB, stream>>>(
            Xb, WqkvT + (size_t)l * 3 * D2, bq + l * 768, bk + l * 768, bv + l * 768,
            Qb, Kb, Vtb, ROWS, 2304, 768, 18);
        attn_mfma<<<dim3(BB * NBLK * HH), 256, 0, stream>>>(Qb, Kb, Vtb, Ctxb);
        gemm128<1><<<dim3(128 * 6), 256, LDSB, stream>>>(
            Ctxb, WoT + l * D2, bo + l * 768, nullptr, nullptr,
            H2f, nullptr, nullptr, ROWS, 768, 768, 6);
        resid_ln<<<dim3(ROWS), 256, 0, stream>>>(H2f, xres, ln1g + l * 768, ln1b + l * 768, AttnF, AttnB);
        gemm128<2><<<dim3(128 * 24), 256, LDSB, stream>>>(
            AttnB, W1T + l * DI, b1 + l * 3072, nullptr, nullptr,
            H1b, nullptr, nullptr, ROWS, 3072, 768, 24);
        gemm128<1><<<dim3(128 * 6), 256, LDSB, stream>>>(
            H1b, W2T + l * DI, b2 + l * 768, nullptr, nullptr,
            H2f, nullptr, nullptr, ROWS, 768, 3072, 6);
        float* outl = out + (size_t)l * AD;
        resid_ln<<<dim3(ROWS), 256, 0, stream>>>(H2f, AttnF, ln2g + l * 768, ln2b + l * 768, outl, Xb);
        xres = outl;
    }
}

// Round 8
// 906.000 us; speedup vs baseline: 1.3498x; 1.0025x over previous
//
#include <hip/hip_runtime.h>
#include <hip/hip_bf16.h>

typedef unsigned short u16;
typedef unsigned int u32;

static const int DD = 768;
static const int SS = 2048;
static const int BB = 8;
static const int HH = 12;
static const int NBLK = 16;   // S / 128
static const int ROWS = BB * SS;          // 16384
static const size_t AD = (size_t)ROWS * DD;   // activation element count
static const size_t D2 = (size_t)DD * DD;
static const size_t DI = (size_t)DD * 3072;

typedef __attribute__((ext_vector_type(8))) short short8;
typedef __attribute__((ext_vector_type(4))) float f32x4;

union U16x8 { uint4 u; short8 s; };

__device__ __forceinline__ float bl(u32 u) { return __uint_as_float(u << 16); }
__device__ __forceinline__ float bh(u32 u) { return __uint_as_float(u & 0xffff0000u); }
__device__ __forceinline__ u16 f2b(float f) {
    u32 u = __float_as_uint(f);
    u += 0x7fffu + ((u >> 16) & 1u);
    return (u16)(u >> 16);
}
__device__ __forceinline__ u32 pack2(float lo, float hi) {
    return (u32)f2b(lo) | ((u32)f2b(hi) << 16);
}

// async global->LDS, 16B per lane (dest is wave-uniform base + lane*16)
__device__ __forceinline__ void gload16(const u16* g, u16* l) {
    __builtin_amdgcn_global_load_lds(
        (const __attribute__((address_space(1))) void*)g,
        (__attribute__((address_space(3))) void*)l, 16, 0, 0);
}

// ---------------- elementwise f32 -> bf16 cast ----------------
__global__ __launch_bounds__(256) void cast_bf16(const float* __restrict__ x,
                                                 u16* __restrict__ xb, int n) {
    int i = (blockIdx.x * 256 + threadIdx.x) * 4;
    if (i < n) {
        float4 v = *reinterpret_cast<const float4*>(x + i);
        uint2 p;
        p.x = pack2(v.x, v.y);
        p.y = pack2(v.z, v.w);
        *reinterpret_cast<uint2*>(xb + i) = p;
    }
}

// ---------------- cast + transpose: W[K,N] f32 -> WT[N,K] bf16 ----------------
__global__ __launch_bounds__(256) void cast_transpose(const float* __restrict__ W,
                                                      u16* __restrict__ WT,
                                                      int K, int N) {
    __shared__ float tile[32][33];
    int bx = blockIdx.x;  // along N
    int by = blockIdx.y;  // along K
    int tx = threadIdx.x; // 0..31
    int ty = threadIdx.y; // 0..7
#pragma unroll
    for (int i = 0; i < 4; i++) {
        int kr = by * 32 + ty + i * 8;
        tile[ty + i * 8][tx] = W[(size_t)kr * N + bx * 32 + tx];
    }
    __syncthreads();
#pragma unroll
    for (int i = 0; i < 4; i++) {
        int nr = bx * 32 + ty + i * 8;
        WT[(size_t)nr * K + by * 32 + tx] = f2b(tile[tx][ty + i * 8]);
    }
}

// ---------------- 128x128 MFMA GEMM, BK=32 dbuf, 4 blocks/CU ----------------
// C[M,N] = A[M,K](bf16) @ BT[N,K](bf16)^T + bias
// EPI 1: f32 out; 2: gelu->bf16 out; 4: fused QKV (band2 -> C2 transposed).
// __launch_bounds__(256,4): cap regs at 128/wave (64 AGPR acc + ~60 VGPR) so
// 4 blocks/CU fit (register-capped at 3 before). LDS 2x16KB = 32KB -> 4/CU.
// Swizzle (rule #21, both sides): 16B-slot phys = logical ^ ((row>>1)&3).
// For 64B rows this is the 2-way-optimal mapping (even rows can only occupy
// bank-quads 0-3, odd rows 4-7; (row>>1) spreads each parity class over its
// 4 quads). Write: pre-swizzled global source; read: sl = ls ^ ((lr>>1)&3).
template <int EPI>
__global__ __launch_bounds__(256, 4) void gemm128(const u16* __restrict__ A,
                                                  const u16* __restrict__ BT,
                                                  const float* __restrict__ b0,
                                                  const float* __restrict__ b1,
                                                  const float* __restrict__ b2,
                                                  void* __restrict__ C0,
                                                  void* __restrict__ C1,
                                                  void* __restrict__ C2,
                                                  int M, int N, int K, int NTN) {
    extern __shared__ u16 smem[];  // 2 slots x 8192 u16 (16KB) = 32KB
    const int tid = threadIdx.x;
    const int nwg = gridDim.x;
    int wg = blockIdx.x;
    // chunked bijective XCD swizzle (all grids divisible by 8)
    wg = (wg & 7) * (nwg >> 3) + (wg >> 3);
    const int tn = wg % NTN, tm = wg / NTN;   // row-major: A M-panel stays hot
    const int m0 = tm * 128, n0 = tn * 128;
    const int lane = tid & 63, w = tid >> 6;
    const int wr = w >> 1, wc = w & 1;
    const int lr = lane & 15, ls = lane >> 4;

    // staging: chunk j covers 64 rows; thread: row r3=tid>>2 in chunk, phys
    // slot c2=tid&3 -> source k-slot (c2 ^ ((r3>>1)&3)); chunk-invariant since
    // 64 rows/chunk keeps (row>>1)&3 unchanged.
    const int r3 = tid >> 2, c2 = tid & 3;
    const int kswz = ((c2 ^ ((r3 >> 1) & 3)) << 3);  // pre-swizzled src k-offset
    const u16* gA = A + (size_t)(m0 + r3) * K + kswz;
    const u16* gB = BT + (size_t)(n0 + r3) * K + kswz;
    const size_t rstep = (size_t)64 * K;       // 64 rows per chunk

    f32x4 acc[4][4];
#pragma unroll
    for (int i = 0; i < 4; i++)
#pragma unroll
        for (int j = 0; j < 4; j++) acc[i][j] = (f32x4){0.f, 0.f, 0.f, 0.f};

    const int NT = K >> 5;
    {   // prologue: stage K-step 0 into slot 0
        u16* pA = smem + tid * 8;
        u16* pB = smem + 4096 + tid * 8;
#pragma unroll
        for (int j = 0; j < 2; j++) {
            gload16(gA + j * rstep, pA + j * 2048);
            gload16(gB + j * rstep, pB + j * 2048);
        }
    }
    __syncthreads();

    for (int t = 0; t < NT; ++t) {
        if (t + 1 < NT) {  // prefetch next K-step into other slot
            const int nb = (t + 1) & 1;
            u16* pA = smem + nb * 8192 + tid * 8;
            u16* pB = smem + nb * 8192 + 4096 + tid * 8;
            const u16* sA = gA + (size_t)(t + 1) * 32;
            const u16* sB = gB + (size_t)(t + 1) * 32;
#pragma unroll
            for (int j = 0; j < 2; j++) {
                gload16(sA + j * rstep, pA + j * 2048);
                gload16(sB + j * rstep, pB + j * 2048);
            }
        }
        const u16* bufA = smem + (t & 1) * 8192 + (wr * 64 + lr) * 32;
        const u16* bufB = smem + (t & 1) * 8192 + 4096 + (wc * 64 + lr) * 32;
        const int sl = ls ^ ((lr >> 1) & 3);   // 2-way-optimal swizzled slot
        U16x8 af[4], bf[4];
#pragma unroll
        for (int ni = 0; ni < 4; ni++)
            bf[ni].u = *(const uint4*)(bufB + ni * 512 + sl * 8);
#pragma unroll
        for (int mi = 0; mi < 4; mi++)
            af[mi].u = *(const uint4*)(bufA + mi * 512 + sl * 8);
#pragma unroll
        for (int mi = 0; mi < 4; mi++)
#pragma unroll
            for (int ni = 0; ni < 4; ni++)
                acc[mi][ni] = __builtin_amdgcn_mfma_f32_16x16x32_bf16(
                    af[mi].s, bf[ni].s, acc[mi][ni], 0, 0, 0);
        __syncthreads();  // drains vmcnt(0): next step landed; cur reads done
    }

    // epilogue
#pragma unroll
    for (int mi = 0; mi < 4; mi++) {
        int row0 = m0 + wr * 64 + mi * 16 + ls * 4;
#pragma unroll
        for (int ni = 0; ni < 4; ni++) {
            int col = n0 + wc * 64 + ni * 16 + lr;
            float v[4];
            if (EPI == 4) {
                int band = col / 768;
                int colq = col - band * 768;
                const float* bp = (band == 0) ? b0 : (band == 1) ? b1 : b2;
                float bs = bp[colq];
#pragma unroll
                for (int r = 0; r < 4; r++) v[r] = acc[mi][ni][r] + bs;
                if (band == 2) {   // V^T: [feature][ROWS]
                    uint2 wv;
                    wv.x = pack2(v[0], v[1]);
                    wv.y = pack2(v[2], v[3]);
                    *reinterpret_cast<uint2*>((u16*)C2 + (size_t)colq * M + row0) = wv;
                } else {
                    u16* dst = (band == 0) ? (u16*)C0 : (u16*)C1;
#pragma unroll
                    for (int r = 0; r < 4; r++)
                        dst[(size_t)(row0 + r) * 768 + colq] = f2b(v[r]);
                }
            } else {
                float bs = b0[col];
#pragma unroll
                for (int r = 0; r < 4; r++) {
                    v[r] = acc[mi][ni][r] + bs;
                    if (EPI == 2) v[r] = 0.5f * v[r] * (1.0f + erff(v[r] * 0.70710678118654752f));
                }
                if (EPI == 1) {
#pragma unroll
                    for (int r = 0; r < 4; r++)
                        ((float*)C0)[(size_t)(row0 + r) * N + col] = v[r];
                } else {
#pragma unroll
                    for (int r = 0; r < 4; r++)
                        ((u16*)C0)[(size_t)(row0 + r) * N + col] = f2b(v[r]);
                }
            }
        }
    }
}

// ---------------- residual add + LayerNorm (writes f32 + bf16) ----------------
__global__ __launch_bounds__(256) void resid_ln(const float* __restrict__ a,
                                                const float* __restrict__ res,
                                                const float* __restrict__ g,
                                                const float* __restrict__ be,
                                                float* __restrict__ of,
                                                u16* __restrict__ ob) {
    __shared__ float red[8];
    const int row = blockIdx.x;
    const int tid = threadIdx.x;
    const size_t base = (size_t)row * 768;
    float v[3];
    float s = 0.f;
#pragma unroll
    for (int i = 0; i < 3; i++) {
        int c = tid + i * 256;
        v[i] = a[base + c] + res[base + c];
        s += v[i];
    }
#pragma unroll
    for (int off = 32; off; off >>= 1) s += __shfl_down(s, off);
    if ((tid & 63) == 0) red[tid >> 6] = s;
    __syncthreads();
    float mean = (red[0] + red[1] + red[2] + red[3]) * (1.f / 768.f);
    float q = 0.f;
#pragma unroll
    for (int i = 0; i < 3; i++) {
        float d = v[i] - mean;
        q += d * d;
    }
#pragma unroll
    for (int off = 32; off; off >>= 1) q += __shfl_down(q, off);
    if ((tid & 63) == 0) red[4 + (tid >> 6)] = q;
    __syncthreads();
    float var = (red[4] + red[5] + red[6] + red[7]) * (1.f / 768.f);
    float inv = rsqrtf(var + 1e-12f);
#pragma unroll
    for (int i = 0; i < 3; i++) {
        int c = tid + i * 256;
        float y = (v[i] - mean) * inv * g[c] + be[c];
        of[base + c] = y;
        ob[base + c] = f2b(y);
    }
}

// ---------------- halo block attention (MFMA) ----------------
__global__ __launch_bounds__(256) void attn_mfma(const u16* __restrict__ Q,
                                                 const u16* __restrict__ Kx,
                                                 const u16* __restrict__ Vt,
                                                 u16* __restrict__ Ctx) {
    __shared__ u16 sm0[128 * 104];  // P (padded stride 104); also K [192][64] swizzled
    __shared__ u16 sm1[64 * 192];   // V^T [64][192] swizzled
    u16* Ks = sm0;
    u16* Ps = sm0;
    u16* Vs = sm1;

    const int bid = blockIdx.x;
    const int h = bid % HH;
    const int n = (bid / HH) % NBLK;
    const int b = bid / (HH * NBLK);
    const int tid = threadIdx.x;
    const int lane = tid & 63, w = tid >> 6;
    const int lr = lane & 15, ls = lane >> 4;
    const int s0 = n * 128 - 32;

#pragma unroll
    for (int j = 0; j < 6; j++) {
        int r = (tid >> 3) + j * 32;
        int c = tid & 7;
        int s = min(max(s0 + r, 0), SS - 1);
        uint4 kv = *reinterpret_cast<const uint4*>(Kx + ((size_t)(b * SS + s)) * 768 + h * 64 + c * 8);
        int byteo = r * 128 + ((c * 16) ^ ((r & 7) << 4));
        *reinterpret_cast<uint4*>(Ks + (byteo >> 1)) = kv;
    }
#pragma unroll
    for (int j = 0; j < 6; j++) {
        int d = tid >> 2;
        int c = (tid & 3) + j * 4;
        int sv = min(max(s0 + c * 8, 0), SS - 8);
        uint4 vv = *reinterpret_cast<const uint4*>(Vt + ((size_t)(h * 64 + d)) * ROWS + b * SS + sv);
        int byteo = d * 384 + ((c * 16) ^ ((d & 7) << 4));
        *reinterpret_cast<uint4*>(Vs + (byteo >> 1)) = vv;
    }
    __syncthreads();

    const int qrow0 = b * SS + n * 128 + w * 32;
    U16x8 qf[2][2];
#pragma unroll
    for (int mi = 0; mi < 2; mi++)
#pragma unroll
        for (int ks = 0; ks < 2; ks++)
            qf[mi][ks].u = *reinterpret_cast<const uint4*>(
                Q + (size_t)(qrow0 + mi * 16 + lr) * 768 + h * 64 + ks * 32 + ls * 8);

    f32x4 sc[2][12];
#pragma unroll
    for (int mi = 0; mi < 2; mi++)
#pragma unroll
        for (int jt = 0; jt < 12; jt++) sc[mi][jt] = (f32x4){0.f, 0.f, 0.f, 0.f};
#pragma unroll
    for (int jt = 0; jt < 12; jt++) {
        U16x8 kf[2];
#pragma unroll
        for (int ks = 0; ks < 2; ks++) {
            int r = jt * 16 + lr;
            int byteo = r * 128 + ((ks * 64 + ls * 16) ^ ((r & 7) << 4));
            kf[ks].u = *reinterpret_cast<const uint4*>(Ks + (byteo >> 1));
        }
#pragma unroll
        for (int mi = 0; mi < 2; mi++)
#pragma unroll
            for (int ks = 0; ks < 2; ks++)
                sc[mi][jt] = __builtin_amdgcn_mfma_f32_16x16x32_bf16(
                    qf[mi][ks].s, kf[ks].s, sc[mi][jt], 0, 0, 0);
    }

    const int lo = (n == 0) ? 32 : 0;
    const int hi = (n == NBLK - 1) ? 160 : 192;
    float mx[2][4], sm[2][4], inv[2][4];
#pragma unroll
    for (int mi = 0; mi < 2; mi++)
#pragma unroll
        for (int r = 0; r < 4; r++) { mx[mi][r] = -3.0e38f; sm[mi][r] = 0.f; }
#pragma unroll
    for (int jt = 0; jt < 12; jt++) {
        int col = jt * 16 + lr;
        bool valid = (col >= lo) && (col < hi);
#pragma unroll
        for (int mi = 0; mi < 2; mi++)
#pragma unroll
            for (int r = 0; r < 4; r++) {
                float v = valid ? sc[mi][jt][r] * 0.125f : -3.0e38f;
                sc[mi][jt][r] = v;
                mx[mi][r] = fmaxf(mx[mi][r], v);
            }
    }
#pragma unroll
    for (int o = 1; o <= 8; o <<= 1)
#pragma unroll
        for (int mi = 0; mi < 2; mi++)
#pragma unroll
            for (int r = 0; r < 4; r++)
                mx[mi][r] = fmaxf(mx[mi][r], __shfl_xor(mx[mi][r], o));
#pragma unroll
    for (int jt = 0; jt < 12; jt++)
#pragma unroll
        for (int mi = 0; mi < 2; mi++)
#pragma unroll
            for (int r = 0; r < 4; r++) {
                float p = __expf(sc[mi][jt][r] - mx[mi][r]);
                sc[mi][jt][r] = p;
                sm[mi][r] += p;
            }
#pragma unroll
    for (int o = 1; o <= 8; o <<= 1)
#pragma unroll
        for (int mi = 0; mi < 2; mi++)
#pragma unroll
            for (int r = 0; r < 4; r++)
                sm[mi][r] += __shfl_xor(sm[mi][r], o);
#pragma unroll
    for (int mi = 0; mi < 2; mi++)
#pragma unroll
        for (int r = 0; r < 4; r++) inv[mi][r] = 1.0f / sm[mi][r];

    f32x4 oacc[2][4];
#pragma unroll
    for (int mi = 0; mi < 2; mi++)
#pragma unroll
        for (int dt = 0; dt < 4; dt++) oacc[mi][dt] = (f32x4){0.f, 0.f, 0.f, 0.f};
    __syncthreads();

#pragma unroll
    for (int ph = 0; ph < 2; ph++) {
#pragma unroll
        for (int jj = 0; jj < 6; jj++) {
            int jt = ph * 6 + jj;
#pragma unroll
            for (int mi = 0; mi < 2; mi++) {
                int row = w * 32 + mi * 16 + ls * 4;
#pragma unroll
                for (int r = 0; r < 4; r++)
                    Ps[(row + r) * 104 + jj * 16 + lr] = f2b(sc[mi][jt][r]);
            }
        }
        __syncthreads();
#pragma unroll
        for (int kk = 0; kk < 3; kk++) {
            U16x8 pf[2], vf[4];
#pragma unroll
            for (int mi = 0; mi < 2; mi++)
                pf[mi].u = *reinterpret_cast<const uint4*>(
                    Ps + (w * 32 + mi * 16 + lr) * 104 + kk * 32 + ls * 8);
#pragma unroll
            for (int dt = 0; dt < 4; dt++) {
                int rrow = dt * 16 + lr;
                int byteo = rrow * 384 + ((ph * 192 + kk * 64 + ls * 16) ^ ((rrow & 7) << 4));
                vf[dt].u = *reinterpret_cast<const uint4*>(Vs + (byteo >> 1));
            }
#pragma unroll
            for (int mi = 0; mi < 2; mi++)
#pragma unroll
                for (int dt = 0; dt < 4; dt++)
                    oacc[mi][dt] = __builtin_amdgcn_mfma_f32_16x16x32_bf16(
                        pf[mi].s, vf[dt].s, oacc[mi][dt], 0, 0, 0);
        }
        __syncthreads();
    }

#pragma unroll
    for (int mi = 0; mi < 2; mi++)
#pragma unroll
        for (int dt = 0; dt < 4; dt++)
#pragma unroll
            for (int r = 0; r < 4; r++) {
                float v = oacc[mi][dt][r] * inv[mi][r];
                Ctx[(size_t)(qrow0 + mi * 16 + ls * 4 + r) * 768 + h * 64 + dt * 16 + lr] = f2b(v);
            }
}

extern "C" void kernel_launch(void* const* d_in, const int* in_sizes, int n_in,
                              void* d_out, int out_size, void* d_ws, size_t ws_size,
                              hipStream_t stream) {
    (void)in_sizes; (void)n_in; (void)out_size; (void)ws_size;
    const float* x    = (const float*)d_in[0];
    const float* Wq   = (const float*)d_in[1];
    const float* bq   = (const float*)d_in[2];
    const float* Wk   = (const float*)d_in[3];
    const float* bk   = (const float*)d_in[4];
    const float* Wv   = (const float*)d_in[5];
    const float* bv   = (const float*)d_in[6];
    const float* Wo   = (const float*)d_in[7];
    const float* bo   = (const float*)d_in[8];
    const float* ln1g = (const float*)d_in[9];
    const float* ln1b = (const float*)d_in[10];
    const float* W1   = (const float*)d_in[11];
    const float* b1   = (const float*)d_in[12];
    const float* W2   = (const float*)d_in[13];
    const float* b2   = (const float*)d_in[14];
    const float* ln2g = (const float*)d_in[15];
    const float* ln2b = (const float*)d_in[16];
    float* out = (float*)d_out;

    char* ws = (char*)d_ws;
    size_t off = 0;
    auto alloc = [&](size_t bytes) -> char* {
        char* p = ws + off;
        off += (bytes + 255) & ~(size_t)255;
        return p;
    };
    u16* WqkvT = (u16*)alloc(2 * 3 * D2 * sizeof(u16));  // per layer: [Q;K;V] rows
    u16* WoT   = (u16*)alloc(2 * D2 * sizeof(u16));
    u16* W1T   = (u16*)alloc(2 * DI * sizeof(u16));
    u16* W2T   = (u16*)alloc(2 * DI * sizeof(u16));
    u16* Xb    = (u16*)alloc(AD * sizeof(u16));
    u16* RegA  = (u16*)alloc(4 * AD * sizeof(u16)); // Qb,Kb,Vt,Ctxb; reused as H1b
    float* AttnF = (float*)alloc(AD * sizeof(float));
    u16*   AttnB = (u16*)alloc(AD * sizeof(u16));
    float* H2f   = (float*)alloc(AD * sizeof(float));
    u16* Qb = RegA;
    u16* Kb = RegA + AD;
    u16* Vtb = RegA + 2 * AD;   // V^T layout: [feature][B*S]
    u16* Ctxb = RegA + 3 * AD;
    u16* H1b = RegA;

    {
        int nelem = ROWS * DD;
        cast_bf16<<<dim3(nelem / 4 / 256), dim3(256), 0, stream>>>(x, Xb, nelem);
    }
    for (int l = 0; l < 2; l++) {
        u16* base = WqkvT + (size_t)l * 3 * D2;
        cast_transpose<<<dim3(24, 24), dim3(32, 8), 0, stream>>>(Wq + l * D2, base, 768, 768);
        cast_transpose<<<dim3(24, 24), dim3(32, 8), 0, stream>>>(Wk + l * D2, base + D2, 768, 768);
        cast_transpose<<<dim3(24, 24), dim3(32, 8), 0, stream>>>(Wv + l * D2, base + 2 * D2, 768, 768);
        cast_transpose<<<dim3(24, 24), dim3(32, 8), 0, stream>>>(Wo + l * D2, WoT + l * D2, 768, 768);
        cast_transpose<<<dim3(96, 24), dim3(32, 8), 0, stream>>>(W1 + l * DI, W1T + l * DI, 768, 3072);
        cast_transpose<<<dim3(24, 96), dim3(32, 8), 0, stream>>>(W2 + l * DI, W2T + l * DI, 3072, 768);
    }

    const size_t LDSB = 32768;
    const float* xres = x;
    for (int l = 0; l < 2; l++) {
        // fused QKV: N=2304 (bands Q|K|V), V written transposed
        gemm128<4><<<dim3(128 * 18), 256, LDSB, stream>>>(
            Xb, WqkvT + (size_t)l * 3 * D2, bq + l * 768, bk + l * 768, bv + l * 768,
            Qb, Kb, Vtb, ROWS, 2304, 768, 18);
        attn_mfma<<<dim3(BB * NBLK * HH), 256, 0, stream>>>(Qb, Kb, Vtb, Ctxb);
        gemm128<1><<<dim3(128 * 6), 256, LDSB, stream>>>(
            Ctxb, WoT + l * D2, bo + l * 768, nullptr, nullptr,
            H2f, nullptr, nullptr, ROWS, 768, 768, 6);
        resid_ln<<<dim3(ROWS), 256, 0, stream>>>(H2f, xres, ln1g + l * 768, ln1b + l * 768, AttnF, AttnB);
        gemm128<2><<<dim3(128 * 24), 256, LDSB, stream>>>(
            AttnB, W1T + l * DI, b1 + l * 3072, nullptr, nullptr,
            H1b, nullptr, nullptr, ROWS, 3072, 768, 24);
        gemm128<1><<<dim3(128 * 6), 256, LDSB, stream>>>(
            H1b, W2T + l * DI, b2 + l * 768, nullptr, nullptr,
            H2f, nullptr, nullptr, ROWS, 768, 3072, 6);
        float* outl = out + (size_t)l * AD;
        resid_ln<<<dim3(ROWS), 256, 0, stream>>>(H2f, AttnF, ln2g + l * 768, ln2b + l * 768, outl, Xb);
        xres = outl;
    }
}

// Round 9
// 881.388 us; speedup vs baseline: 1.3875x; 1.0279x over previous
//
#include <hip/hip_runtime.h>
#include <hip/hip_bf16.h>

typedef unsigned short u16;
typedef unsigned int u32;

static const int DD = 768;
static const int SS = 2048;
static const int BB = 8;
static const int HH = 12;
static const int NBLK = 16;   // S / 128
static const int ROWS = BB * SS;          // 16384
static const size_t AD = (size_t)ROWS * DD;   // activation element count
static const size_t D2 = (size_t)DD * DD;
static const size_t DI = (size_t)DD * 3072;

typedef __attribute__((ext_vector_type(8))) short short8;
typedef __attribute__((ext_vector_type(4))) float f32x4;

union U16x8 { uint4 u; short8 s; };

__device__ __forceinline__ float bl(u32 u) { return __uint_as_float(u << 16); }
__device__ __forceinline__ float bh(u32 u) { return __uint_as_float(u & 0xffff0000u); }
__device__ __forceinline__ u16 f2b(float f) {
    u32 u = __float_as_uint(f);
    u += 0x7fffu + ((u >> 16) & 1u);
    return (u16)(u >> 16);
}
__device__ __forceinline__ u32 pack2(float lo, float hi) {
    return (u32)f2b(lo) | ((u32)f2b(hi) << 16);
}

// async global->LDS, 16B per lane (dest is wave-uniform base + lane*16)
__device__ __forceinline__ void gload16(const u16* g, u16* l) {
    __builtin_amdgcn_global_load_lds(
        (const __attribute__((address_space(1))) void*)g,
        (__attribute__((address_space(3))) void*)l, 16, 0, 0);
}

// fast GELU (tanh form): v * sigmoid(2z), z = 0.7978845608(v + 0.044715 v^3)
// max abs dev from erf-gelu ~3e-4, far below bf16 output threshold.
__device__ __forceinline__ float gelu_fast(float v) {
    float z2 = 1.5957691216f * (v + 0.044715f * v * v * v);
    z2 = fminf(z2, 80.f);                 // avoid inf/inf
    float e = __expf(z2);
    return v * (e / (e + 1.0f));
}

// ---------------- elementwise f32 -> bf16 cast ----------------
__global__ __launch_bounds__(256) void cast_bf16(const float* __restrict__ x,
                                                 u16* __restrict__ xb, int n) {
    int i = (blockIdx.x * 256 + threadIdx.x) * 4;
    if (i < n) {
        float4 v = *reinterpret_cast<const float4*>(x + i);
        uint2 p;
        p.x = pack2(v.x, v.y);
        p.y = pack2(v.z, v.w);
        *reinterpret_cast<uint2*>(xb + i) = p;
    }
}

// ---------------- cast + transpose: W[K,N] f32 -> WT[N,K] bf16 ----------------
__global__ __launch_bounds__(256) void cast_transpose(const float* __restrict__ W,
                                                      u16* __restrict__ WT,
                                                      int K, int N) {
    __shared__ float tile[32][33];
    int bx = blockIdx.x;  // along N
    int by = blockIdx.y;  // along K
    int tx = threadIdx.x; // 0..31
    int ty = threadIdx.y; // 0..7
#pragma unroll
    for (int i = 0; i < 4; i++) {
        int kr = by * 32 + ty + i * 8;
        tile[ty + i * 8][tx] = W[(size_t)kr * N + bx * 32 + tx];
    }
    __syncthreads();
#pragma unroll
    for (int i = 0; i < 4; i++) {
        int nr = bx * 32 + ty + i * 8;
        WT[(size_t)nr * K + by * 32 + tx] = f2b(tile[tx][ty + i * 8]);
    }
}

// ---------------- 128x128 MFMA GEMM, BK=32 dbuf, 4 blocks/CU ----------------
// C[M,N] = A[M,K](bf16) @ BT[N,K](bf16)^T + bias
// EPI 0: bf16 out; 2: gelu->bf16 out; 5: QKV row-major (band uniform per block)
// Swizzle (rule #21, both sides): 16B-slot phys = logical ^ ((row>>1)&3).
template <int EPI>
__global__ __launch_bounds__(256, 4) void gemm128(const u16* __restrict__ A,
                                                  const u16* __restrict__ BT,
                                                  const float* __restrict__ b0,
                                                  const float* __restrict__ b1,
                                                  const float* __restrict__ b2,
                                                  void* __restrict__ C0,
                                                  void* __restrict__ C1,
                                                  void* __restrict__ C2,
                                                  int M, int N, int K, int NTN) {
    extern __shared__ u16 smem[];  // 2 slots x 8192 u16 (16KB) = 32KB
    const int tid = threadIdx.x;
    const int nwg = gridDim.x;
    int wg = blockIdx.x;
    // chunked bijective XCD swizzle (all grids divisible by 8)
    wg = (wg & 7) * (nwg >> 3) + (wg >> 3);
    const int tn = wg % NTN, tm = wg / NTN;   // row-major: A M-panel stays hot
    const int m0 = tm * 128, n0 = tn * 128;
    const int lane = tid & 63, w = tid >> 6;
    const int wr = w >> 1, wc = w & 1;
    const int lr = lane & 15, ls = lane >> 4;

    const int r3 = tid >> 2, c2 = tid & 3;
    const int kswz = ((c2 ^ ((r3 >> 1) & 3)) << 3);  // pre-swizzled src k-offset
    const u16* gA = A + (size_t)(m0 + r3) * K + kswz;
    const u16* gB = BT + (size_t)(n0 + r3) * K + kswz;
    const size_t rstep = (size_t)64 * K;       // 64 rows per chunk

    f32x4 acc[4][4];
#pragma unroll
    for (int i = 0; i < 4; i++)
#pragma unroll
        for (int j = 0; j < 4; j++) acc[i][j] = (f32x4){0.f, 0.f, 0.f, 0.f};

    const int NT = K >> 5;
    {   // prologue: stage K-step 0 into slot 0
        u16* pA = smem + tid * 8;
        u16* pB = smem + 4096 + tid * 8;
#pragma unroll
        for (int j = 0; j < 2; j++) {
            gload16(gA + j * rstep, pA + j * 2048);
            gload16(gB + j * rstep, pB + j * 2048);
        }
    }
    __syncthreads();

    for (int t = 0; t < NT; ++t) {
        if (t + 1 < NT) {  // prefetch next K-step into other slot
            const int nb = (t + 1) & 1;
            u16* pA = smem + nb * 8192 + tid * 8;
            u16* pB = smem + nb * 8192 + 4096 + tid * 8;
            const u16* sA = gA + (size_t)(t + 1) * 32;
            const u16* sB = gB + (size_t)(t + 1) * 32;
#pragma unroll
            for (int j = 0; j < 2; j++) {
                gload16(sA + j * rstep, pA + j * 2048);
                gload16(sB + j * rstep, pB + j * 2048);
            }
        }
        const u16* bufA = smem + (t & 1) * 8192 + (wr * 64 + lr) * 32;
        const u16* bufB = smem + (t & 1) * 8192 + 4096 + (wc * 64 + lr) * 32;
        const int sl = ls ^ ((lr >> 1) & 3);   // 2-way-optimal swizzled slot
        U16x8 af[4], bf[4];
#pragma unroll
        for (int ni = 0; ni < 4; ni++)
            bf[ni].u = *(const uint4*)(bufB + ni * 512 + sl * 8);
#pragma unroll
        for (int mi = 0; mi < 4; mi++)
            af[mi].u = *(const uint4*)(bufA + mi * 512 + sl * 8);
#pragma unroll
        for (int mi = 0; mi < 4; mi++)
#pragma unroll
            for (int ni = 0; ni < 4; ni++)
                acc[mi][ni] = __builtin_amdgcn_mfma_f32_16x16x32_bf16(
                    af[mi].s, bf[ni].s, acc[mi][ni], 0, 0, 0);
        __syncthreads();  // drains vmcnt(0): next step landed; cur reads done
    }

    // epilogue
    u16* dstQ = (u16*)C0;
    const float* bp = b0;
    int cbase = 0;
    if (EPI == 5) {                    // band uniform per block (768 % 128 == 0)
        int band = n0 / 768;
        dstQ = (band == 0) ? (u16*)C0 : (band == 1) ? (u16*)C1 : (u16*)C2;
        bp = (band == 0) ? b0 : (band == 1) ? b1 : b2;
        cbase = n0 - band * 768;
    }
#pragma unroll
    for (int mi = 0; mi < 4; mi++) {
        int row0 = m0 + wr * 64 + mi * 16 + ls * 4;
#pragma unroll
        for (int ni = 0; ni < 4; ni++) {
            int cloc = wc * 64 + ni * 16 + lr;
            float v[4];
            if (EPI == 5) {
                float bs = bp[cbase + cloc];
#pragma unroll
                for (int r = 0; r < 4; r++) {
                    v[r] = acc[mi][ni][r] + bs;
                    dstQ[(size_t)(row0 + r) * 768 + cbase + cloc] = f2b(v[r]);
                }
            } else {
                int col = n0 + cloc;
                float bs = b0[col];
#pragma unroll
                for (int r = 0; r < 4; r++) {
                    v[r] = acc[mi][ni][r] + bs;
                    if (EPI == 2) v[r] = gelu_fast(v[r]);
                    ((u16*)C0)[(size_t)(row0 + r) * N + col] = f2b(v[r]);
                }
            }
        }
    }
}

// ---------------- residual add + LayerNorm (bf16 a + f32 res -> f32 + bf16) ----
__global__ __launch_bounds__(256) void resid_ln(const u16* __restrict__ a,
                                                const float* __restrict__ res,
                                                const float* __restrict__ g,
                                                const float* __restrict__ be,
                                                float* __restrict__ of,
                                                u16* __restrict__ ob) {
    __shared__ float red[8];
    const int row = blockIdx.x;
    const int tid = threadIdx.x;
    const size_t base = (size_t)row * 768;
    float v[3];
    float s = 0.f;
#pragma unroll
    for (int i = 0; i < 3; i++) {
        int c = tid + i * 256;
        v[i] = bl((u32)a[base + c]) + res[base + c];
        s += v[i];
    }
#pragma unroll
    for (int off = 32; off; off >>= 1) s += __shfl_down(s, off);
    if ((tid & 63) == 0) red[tid >> 6] = s;
    __syncthreads();
    float mean = (red[0] + red[1] + red[2] + red[3]) * (1.f / 768.f);
    float q = 0.f;
#pragma unroll
    for (int i = 0; i < 3; i++) {
        float d = v[i] - mean;
        q += d * d;
    }
#pragma unroll
    for (int off = 32; off; off >>= 1) q += __shfl_down(q, off);
    if ((tid & 63) == 0) red[4 + (tid >> 6)] = q;
    __syncthreads();
    float var = (red[4] + red[5] + red[6] + red[7]) * (1.f / 768.f);
    float inv = rsqrtf(var + 1e-12f);
#pragma unroll
    for (int i = 0; i < 3; i++) {
        int c = tid + i * 256;
        float y = (v[i] - mean) * inv * g[c] + be[c];
        of[base + c] = y;
        ob[base + c] = f2b(y);
    }
}

// ---------------- halo block attention (MFMA) ----------------
// Q, K, V all row-major [B*S][768] bf16. V transposed into LDS at stage time.
__global__ __launch_bounds__(256) void attn_mfma(const u16* __restrict__ Q,
                                                 const u16* __restrict__ Kx,
                                                 const u16* __restrict__ Vx,
                                                 u16* __restrict__ Ctx) {
    __shared__ u16 sm0[128 * 104];  // P (padded stride 104); also K [192][64] swizzled
    __shared__ u16 sm1[64 * 192];   // V^T [64 feat][192 tok] chunk-swizzled
    u16* Ks = sm0;
    u16* Ps = sm0;
    u16* Vs = sm1;

    const int bid = blockIdx.x;
    const int h = bid % HH;
    const int n = (bid / HH) % NBLK;
    const int b = bid / (HH * NBLK);
    const int tid = threadIdx.x;
    const int lane = tid & 63, w = tid >> 6;
    const int lr = lane & 15, ls = lane >> 4;
    const int s0 = n * 128 - 32;

    // K window: rows j (tokens), cols d; row-swizzled for conflict-free b128 reads
#pragma unroll
    for (int j = 0; j < 6; j++) {
        int r = (tid >> 3) + j * 32;
        int c = tid & 7;
        int s = min(max(s0 + r, 0), SS - 1);
        uint4 kv = *reinterpret_cast<const uint4*>(Kx + ((size_t)(b * SS + s)) * 768 + h * 64 + c * 8);
        int byteo = r * 128 + ((c * 16) ^ ((r & 7) << 4));
        *reinterpret_cast<uint4*>(Ks + (byteo >> 1)) = kv;
    }
    // V^T window: coalesced row-major global read, per-element LDS transpose.
    // element (feature d, window token j): byte = d*384 + pchunk*16 + (j&7)*2,
    // pchunk = (j>>3) ^ (d&7) ^ ((d>>3)&7)   (<=2-way on write and read)
#pragma unroll
    for (int j = 0; j < 6; j++) {
        int r = (tid >> 3) + j * 32;          // window token
        int c = tid & 7;                      // feature chunk (8 features)
        int s = min(max(s0 + r, 0), SS - 1);
        uint4 vv = *reinterpret_cast<const uint4*>(Vx + ((size_t)(b * SS + s)) * 768 + h * 64 + c * 8);
        const u16* e = reinterpret_cast<const u16*>(&vv);
        int chunk = r >> 3;
        int bo = (r & 7) * 2;
#pragma unroll
        for (int i = 0; i < 8; i++) {
            int d = c * 8 + i;
            int pch = chunk ^ (d & 7) ^ ((d >> 3) & 7);
            Vs[(d * 384 + pch * 16 + bo) >> 1] = e[i];
        }
    }
    __syncthreads();

    const int qrow0 = b * SS + n * 128 + w * 32;
    U16x8 qf[2][2];
#pragma unroll
    for (int mi = 0; mi < 2; mi++)
#pragma unroll
        for (int ks = 0; ks < 2; ks++)
            qf[mi][ks].u = *reinterpret_cast<const uint4*>(
                Q + (size_t)(qrow0 + mi * 16 + lr) * 768 + h * 64 + ks * 32 + ls * 8);

    f32x4 sc[2][12];
#pragma unroll
    for (int mi = 0; mi < 2; mi++)
#pragma unroll
        for (int jt = 0; jt < 12; jt++) sc[mi][jt] = (f32x4){0.f, 0.f, 0.f, 0.f};
#pragma unroll
    for (int jt = 0; jt < 12; jt++) {
        U16x8 kf[2];
#pragma unroll
        for (int ks = 0; ks < 2; ks++) {
            int r = jt * 16 + lr;
            int byteo = r * 128 + ((ks * 64 + ls * 16) ^ ((r & 7) << 4));
            kf[ks].u = *reinterpret_cast<const uint4*>(Ks + (byteo >> 1));
        }
#pragma unroll
        for (int mi = 0; mi < 2; mi++)
#pragma unroll
            for (int ks = 0; ks < 2; ks++)
                sc[mi][jt] = __builtin_amdgcn_mfma_f32_16x16x32_bf16(
                    qf[mi][ks].s, kf[ks].s, sc[mi][jt], 0, 0, 0);
    }

    const int lo = (n == 0) ? 32 : 0;
    const int hi = (n == NBLK - 1) ? 160 : 192;
    float mx[2][4], sm[2][4], inv[2][4];
#pragma unroll
    for (int mi = 0; mi < 2; mi++)
#pragma unroll
        for (int r = 0; r < 4; r++) { mx[mi][r] = -3.0e38f; sm[mi][r] = 0.f; }
#pragma unroll
    for (int jt = 0; jt < 12; jt++) {
        int col = jt * 16 + lr;
        bool valid = (col >= lo) && (col < hi);
#pragma unroll
        for (int mi = 0; mi < 2; mi++)
#pragma unroll
            for (int r = 0; r < 4; r++) {
                float v = valid ? sc[mi][jt][r] * 0.125f : -3.0e38f;
                sc[mi][jt][r] = v;
                mx[mi][r] = fmaxf(mx[mi][r], v);
            }
    }
#pragma unroll
    for (int o = 1; o <= 8; o <<= 1)
#pragma unroll
        for (int mi = 0; mi < 2; mi++)
#pragma unroll
            for (int r = 0; r < 4; r++)
                mx[mi][r] = fmaxf(mx[mi][r], __shfl_xor(mx[mi][r], o));
#pragma unroll
    for (int jt = 0; jt < 12; jt++)
#pragma unroll
        for (int mi = 0; mi < 2; mi++)
#pragma unroll
            for (int r = 0; r < 4; r++) {
                float p = __expf(sc[mi][jt][r] - mx[mi][r]);
                sc[mi][jt][r] = p;
                sm[mi][r] += p;
            }
#pragma unroll
    for (int o = 1; o <= 8; o <<= 1)
#pragma unroll
        for (int mi = 0; mi < 2; mi++)
#pragma unroll
            for (int r = 0; r < 4; r++)
                sm[mi][r] += __shfl_xor(sm[mi][r], o);
#pragma unroll
    for (int mi = 0; mi < 2; mi++)
#pragma unroll
        for (int r = 0; r < 4; r++) inv[mi][r] = 1.0f / sm[mi][r];

    f32x4 oacc[2][4];
#pragma unroll
    for (int mi = 0; mi < 2; mi++)
#pragma unroll
        for (int dt = 0; dt < 4; dt++) oacc[mi][dt] = (f32x4){0.f, 0.f, 0.f, 0.f};
    __syncthreads();

#pragma unroll
    for (int ph = 0; ph < 2; ph++) {
#pragma unroll
        for (int jj = 0; jj < 6; jj++) {
            int jt = ph * 6 + jj;
#pragma unroll
            for (int mi = 0; mi < 2; mi++) {
                int row = w * 32 + mi * 16 + ls * 4;
#pragma unroll
                for (int r = 0; r < 4; r++)
                    Ps[(row + r) * 104 + jj * 16 + lr] = f2b(sc[mi][jt][r]);
            }
        }
        __syncthreads();
#pragma unroll
        for (int kk = 0; kk < 3; kk++) {
            U16x8 pf[2], vf[4];
#pragma unroll
            for (int mi = 0; mi < 2; mi++)
                pf[mi].u = *reinterpret_cast<const uint4*>(
                    Ps + (w * 32 + mi * 16 + lr) * 104 + kk * 32 + ls * 8);
#pragma unroll
            for (int dt = 0; dt < 4; dt++) {
                int rrow = dt * 16 + lr;
                int lch = ph * 12 + kk * 4 + ls;
                int pch = lch ^ (rrow & 7) ^ ((rrow >> 3) & 7);
                vf[dt].u = *reinterpret_cast<const uint4*>(Vs + ((rrow * 384 + pch * 16) >> 1));
            }
#pragma unroll
            for (int mi = 0; mi < 2; mi++)
#pragma unroll
                for (int dt = 0; dt < 4; dt++)
                    oacc[mi][dt] = __builtin_amdgcn_mfma_f32_16x16x32_bf16(
                        pf[mi].s, vf[dt].s, oacc[mi][dt], 0, 0, 0);
        }
        __syncthreads();
    }

#pragma unroll
    for (int mi = 0; mi < 2; mi++)
#pragma unroll
        for (int dt = 0; dt < 4; dt++)
#pragma unroll
            for (int r = 0; r < 4; r++) {
                float v = oacc[mi][dt][r] * inv[mi][r];
                Ctx[(size_t)(qrow0 + mi * 16 + ls * 4 + r) * 768 + h * 64 + dt * 16 + lr] = f2b(v);
            }
}

extern "C" void kernel_launch(void* const* d_in, const int* in_sizes, int n_in,
                              void* d_out, int out_size, void* d_ws, size_t ws_size,
                              hipStream_t stream) {
    (void)in_sizes; (void)n_in; (void)out_size; (void)ws_size;
    const float* x    = (const float*)d_in[0];
    const float* Wq   = (const float*)d_in[1];
    const float* bq   = (const float*)d_in[2];
    const float* Wk   = (const float*)d_in[3];
    const float* bk   = (const float*)d_in[4];
    const float* Wv   = (const float*)d_in[5];
    const float* bv   = (const float*)d_in[6];
    const float* Wo   = (const float*)d_in[7];
    const float* bo   = (const float*)d_in[8];
    const float* ln1g = (const float*)d_in[9];
    const float* ln1b = (const float*)d_in[10];
    const float* W1   = (const float*)d_in[11];
    const float* b1   = (const float*)d_in[12];
    const float* W2   = (const float*)d_in[13];
    const float* b2   = (const float*)d_in[14];
    const float* ln2g = (const float*)d_in[15];
    const float* ln2b = (const float*)d_in[16];
    float* out = (float*)d_out;

    char* ws = (char*)d_ws;
    size_t off = 0;
    auto alloc = [&](size_t bytes) -> char* {
        char* p = ws + off;
        off += (bytes + 255) & ~(size_t)255;
        return p;
    };
    u16* WqkvT = (u16*)alloc(2 * 3 * D2 * sizeof(u16));  // per layer: [Q;K;V] rows
    u16* WoT   = (u16*)alloc(2 * D2 * sizeof(u16));
    u16* W1T   = (u16*)alloc(2 * DI * sizeof(u16));
    u16* W2T   = (u16*)alloc(2 * DI * sizeof(u16));
    u16* Xb    = (u16*)alloc(AD * sizeof(u16));
    u16* RegA  = (u16*)alloc(4 * AD * sizeof(u16)); // Qb,Kb,Vb,Ctxb; reused as H1b
    float* AttnF = (float*)alloc(AD * sizeof(float));
    u16*   AttnB = (u16*)alloc(AD * sizeof(u16));
    u16*   H2b   = (u16*)alloc(AD * sizeof(u16));
    u16* Qb = RegA;
    u16* Kb = RegA + AD;
    u16* Vb = RegA + 2 * AD;    // row-major like Q/K
    u16* Ctxb = RegA + 3 * AD;
    u16* H1b = RegA;

    {
        int nelem = ROWS * DD;
        cast_bf16<<<dim3(nelem / 4 / 256), dim3(256), 0, stream>>>(x, Xb, nelem);
    }
    for (int l = 0; l < 2; l++) {
        u16* base = WqkvT + (size_t)l * 3 * D2;
        cast_transpose<<<dim3(24, 24), dim3(32, 8), 0, stream>>>(Wq + l * D2, base, 768, 768);
        cast_transpose<<<dim3(24, 24), dim3(32, 8), 0, stream>>>(Wk + l * D2, base + D2, 768, 768);
        cast_transpose<<<dim3(24, 24), dim3(32, 8), 0, stream>>>(Wv + l * D2, base + 2 * D2, 768, 768);
        cast_transpose<<<dim3(24, 24), dim3(32, 8), 0, stream>>>(Wo + l * D2, WoT + l * D2, 768, 768);
        cast_transpose<<<dim3(96, 24), dim3(32, 8), 0, stream>>>(W1 + l * DI, W1T + l * DI, 768, 3072);
        cast_transpose<<<dim3(24, 96), dim3(32, 8), 0, stream>>>(W2 + l * DI, W2T + l * DI, 3072, 768);
    }

    const size_t LDSB = 32768;
    const float* xres = x;
    for (int l = 0; l < 2; l++) {
        // fused QKV: N=2304 (bands Q|K|V), all outputs row-major bf16
        gemm128<5><<<dim3(128 * 18), 256, LDSB, stream>>>(
            Xb, WqkvT + (size_t)l * 3 * D2, bq + l * 768, bk + l * 768, bv + l * 768,
            Qb, Kb, Vb, ROWS, 2304, 768, 18);
        attn_mfma<<<dim3(BB * NBLK * HH), 256, 0, stream>>>(Qb, Kb, Vb, Ctxb);
        gemm128<0><<<dim3(128 * 6), 256, LDSB, stream>>>(
            Ctxb, WoT + l * D2, bo + l * 768, nullptr, nullptr,
            H2b, nullptr, nullptr, ROWS, 768, 768, 6);
        resid_ln<<<dim3(ROWS), 256, 0, stream>>>(H2b, xres, ln1g + l * 768, ln1b + l * 768, AttnF, AttnB);
        gemm128<2><<<dim3(128 * 24), 256, LDSB, stream>>>(
            AttnB, W1T + l * DI, b1 + l * 3072, nullptr, nullptr,
            H1b, nullptr, nullptr, ROWS, 3072, 768, 24);
        gemm128<0><<<dim3(128 * 6), 256, LDSB, stream>>>(
            H1b, W2T + l * DI, b2 + l * 768, nullptr, nullptr,
            H2b, nullptr, nullptr, ROWS, 768, 3072, 6);
        float* outl = out + (size_t)l * AD;
        resid_ln<<<dim3(ROWS), 256, 0, stream>>>(H2b, AttnF, ln2g + l * 768, ln2b + l * 768, outl, Xb);
        xres = outl;
    }
}